// Round 10
// baseline (114.248 us; speedup 1.0000x reference)
//
#include <hip/hip_runtime.h>
#include <math.h>

// YIN pitch, MI355X. Constants from reference:
//   SR=16000, STRIDES=160, W=257, TAU_MAX=213, TAU_MIN=26, C=187, MEDIAN=30
#define T_LEN    160000
#define STRIDES  160
#define NF       1001
#define NB       64
#define TAU_MINC 26
#define C_LEN    187
#define NFRAMES  (NB * NF)     // 64064

// Per-wave LDS map (floats). Sequential lifetimes (wave-synchronous):
//   [0,292)    SH: f16 signal, 292 padded u32. Dead after phase 3.
//   [0,572)    part: phase-4 partials (2 groups after shfl pre-reduce). Aliases SH.
//   [584,841)  CS: cumsum of squares, 257 floats.
#define WAVE_F  848
#define CS_B    584
#define PCHUNK2(gg, q, ii) ((gg) * 73 + (q) * 18 + (ii))   // chunk idx, max 142

// Padded u32 index for the f16 signal: one 16B chunk inserted every 32 u32 so
// the 16 ii-lanes' window reads (u32 stride 8) spread across bank-quads.
#define SLOTU(U) ((U) + 4 * ((U) >> 5))

// clang's AMDGPU builtins use __fp16 vectors:
//   __builtin_amdgcn_cvt_pkrtz : (float,float) -> V2h
//   __builtin_amdgcn_fdot2     : (V2h, V2h, float, bool) -> float
typedef __fp16 half2_t __attribute__((ext_vector_type(2)));
union H2U { half2_t h; unsigned int u; };

__device__ __forceinline__ unsigned int pack2h(float a, float b) {
    H2U x;
#if __has_builtin(__builtin_amdgcn_cvt_pkrtz)
    x.h = __builtin_amdgcn_cvt_pkrtz(a, b);
#else
    x.h.x = (__fp16)a; x.h.y = (__fp16)b;
#endif
    return x.u;
}

__device__ __forceinline__ float fdot2f(unsigned int a, unsigned int b, float c) {
    H2U ua, ub; ua.u = a; ub.u = b;
#if __has_builtin(__builtin_amdgcn_fdot2)
    return __builtin_amdgcn_fdot2(ua.h, ub.h, c, false);
#else
    return c + (float)ua.h.x * (float)ub.h.x + (float)ua.h.y * (float)ub.h.y;
#endif
}

__device__ __forceinline__ float loH(unsigned int u) { H2U t; t.u = u; return (float)t.h.x; }
__device__ __forceinline__ float hiH(unsigned int u) { H2U t; t.u = u; return (float)t.h.y; }

__device__ __forceinline__ float frcp(float x) {
#if __has_builtin(__builtin_amdgcn_rcpf)
    return __builtin_amdgcn_rcpf(x);
#else
    return 1.0f / x;
#endif
}

// ---- DPP wave-inclusive scan (VALU pipe, no LDS): row_shr 1/2/4/8 then
// row_bcast15 (rows 1,3) and row_bcast31 (rows 2,3). old=0 so masked/OOB adds 0.
template<int CTRL, int RMASK, bool BC>
__device__ __forceinline__ float dpp_add(float v) {
    union { float f; int i; } a, r;
    a.f = v;
    r.i = __builtin_amdgcn_update_dpp(0, a.i, CTRL, RMASK, 0xF, BC);
    return v + r.f;
}
__device__ __forceinline__ float wave_iscan_add(float x) {
    float v = x;
    v = dpp_add<0x111, 0xF, true>(v);    // row_shr:1
    v = dpp_add<0x112, 0xF, true>(v);    // row_shr:2
    v = dpp_add<0x114, 0xF, true>(v);    // row_shr:4
    v = dpp_add<0x118, 0xF, true>(v);    // row_shr:8
    v = dpp_add<0x142, 0xA, false>(v);   // row_bcast:15 -> rows 1,3
    v = dpp_add<0x143, 0xC, false>(v);   // row_bcast:31 -> rows 2,3
    return v;
}

// odd-pair from two aligned pairs: (halfs 2i+1, 2i+2)
#define AB(HI, LO) ((unsigned int)(((LO) >> 16) | ((HI) << 16)))

// R2-R4 lesson: arrays with computed indices survive SROA as allocas ->
// scratch -> 6 GB HBM. Hot loop uses ONLY named scalars (proven R5/R6/R8).

__global__ __launch_bounds__(128, 7) void yin_frames(const float* __restrict__ in,
                                                     float* __restrict__ pitch) {
    __shared__ __align__(16) float SB_[2][WAVE_F];

    const int wid  = threadIdx.x >> 6;
    const int lane = threadIdx.x & 63;
    const int frame = blockIdx.x * 2 + wid;
    const int b = frame / NF;
    const int f = frame - b * NF;
    float* SB = SB_[wid];
    unsigned int* SHu = (unsigned int*)SB;

    // ---------------- phase 1: zero padded f16 region + stage frame --------------
    {
        uint4 z; z.x = 0u; z.y = 0u; z.z = 0u; z.w = 0u;
        *(uint4*)(SHu + 4 * lane) = z;                      // u32 [0,256)
        if (lane < 9) *(uint4*)(SHu + 256 + 4 * lane) = z;  // u32 [256,292)
    }
    const float* src = in + (size_t)b * T_LEN;
    const int start = f * STRIDES;
    int e0 = start + 4 * lane;
    float4 q;
    if (e0 + 3 < T_LEN) {
        q = *(const float4*)(src + e0);
    } else {
        q.x = (e0 + 0 < T_LEN) ? src[e0 + 0] : 0.f;
        q.y = (e0 + 1 < T_LEN) ? src[e0 + 1] : 0.f;
        q.z = (e0 + 2 < T_LEN) ? src[e0 + 2] : 0.f;
        q.w = (e0 + 3 < T_LEN) ? src[e0 + 3] : 0.f;
    }
    {   // halfs 4l..4l+3 at padded u32 2l; pair doesn't cross a pad chunk
        uint2 d; d.x = pack2h(q.x, q.y); d.y = pack2h(q.z, q.w);
        *(uint2*)(SHu + 2 * lane + 4 * (lane >> 4)) = d;
    }
    float s256f = 0.0f;
    if (lane == 0) {
        int e2 = start + 256;
        s256f = (e2 < T_LEN) ? src[e2] : 0.f;
        SHu[SLOTU(128)] = pack2h(s256f, 0.f);               // halfs 256,257
    }
    s256f = __shfl(s256f, 0);

    // ---------------- phase 2: cumsum of squares (fp32, DPP scan) ----------------
    float p0 = q.x * q.x;
    float p1 = p0 + q.y * q.y;
    float p2 = p1 + q.z * q.z;
    float p3 = p2 + q.w * q.w;
    float sc = wave_iscan_add(p3);
    const float csbase = sc - p3;
    const float csx = csbase + p0, csy = csbase + p1, csz = csbase + p2, csw_ = csbase + p3;
    {
        float4 csw4; csw4.x = csx; csw4.y = csy; csw4.z = csz; csw4.w = csw_;
        *(float4*)(SB + CS_B + 4 * lane) = csw4;            // for reversed reads
    }
    float totE = __shfl(sc, 63) + s256f * s256f;
    if (lane == 63) SB[CS_B + 256] = totE;

    // ---------------- phase 3: autocorr via v_dot2_f32_f16 -----------------------
    // lane = (g,ii): g covers j in [64g,64g+64), ii covers taus 16ii..16ii+15.
    // Even tau 2e:  dot2(c_aligned_p, w_{p+e}).  Odd tau 2e+1: dot2(c_odd_p,
    // w_{p+e+1}); odd-c covers j in [64g+1,64g+65) -> telescopes; missing
    // x[0]*x[tau] term added as odd-A init on g==0 lanes.
    const int g  = lane >> 4;
    const int ii = lane & 15;
    const int W0u = 32 * g + 8 * ii;                        // unpadded u32 window base
    const int cb  = 36 * g;                                 // padded u32 base of c region

    unsigned int aw0, aw1, aw2, aw3, aw4, aw5, aw6, aw7, aw8, aw9;
    unsigned int aw10, aw11, aw12, aw13, aw14, aw15, aw16, aw17, aw18, aw19;
    {
        uint4 t;
        t = *(const uint4*)(SHu + SLOTU(W0u + 0));  aw0  = t.x; aw1  = t.y; aw2  = t.z; aw3  = t.w;
        t = *(const uint4*)(SHu + SLOTU(W0u + 4));  aw4  = t.x; aw5  = t.y; aw6  = t.z; aw7  = t.w;
        t = *(const uint4*)(SHu + SLOTU(W0u + 8));  aw8  = t.x; aw9  = t.y; aw10 = t.z; aw11 = t.w;
        t = *(const uint4*)(SHu + SLOTU(W0u + 12)); aw12 = t.x; aw13 = t.y; aw14 = t.z; aw15 = t.w;
        t = *(const uint4*)(SHu + SLOTU(W0u + 16)); aw16 = t.x; aw17 = t.y; aw18 = t.z; aw19 = t.w;
    }
    uint4 cvq = *(const uint4*)(SHu + cb);

    // odd-A init = missing j=0 term (g==0 lanes only); evens init 0.
    const float x0f = loH(SHu[0]);
    const bool g0 = (g == 0);
    float A0 = 0.f,                                A1  = g0 ? x0f * hiH(aw0) : 0.f;
    float A2 = 0.f,                                A3  = g0 ? x0f * hiH(aw1) : 0.f;
    float A4 = 0.f,                                A5  = g0 ? x0f * hiH(aw2) : 0.f;
    float A6 = 0.f,                                A7  = g0 ? x0f * hiH(aw3) : 0.f;
    float A8 = 0.f,                                A9  = g0 ? x0f * hiH(aw4) : 0.f;
    float A10 = 0.f,                               A11 = g0 ? x0f * hiH(aw5) : 0.f;
    float A12 = 0.f,                               A13 = g0 ? x0f * hiH(aw6) : 0.f;
    float A14 = 0.f,                               A15 = g0 ? x0f * hiH(aw7) : 0.f;

// A_{2e} += dot2(CA, X_{e}); A_{2e+1} += dot2(CO, X_{e+1})
#define PSTEP(CA, CO, X0, X1, X2, X3, X4, X5, X6, X7, X8)                        \
    A0  = fdot2f(CA, X0, A0);   A1  = fdot2f(CO, X1, A1);                        \
    A2  = fdot2f(CA, X1, A2);   A3  = fdot2f(CO, X2, A3);                        \
    A4  = fdot2f(CA, X2, A4);   A5  = fdot2f(CO, X3, A5);                        \
    A6  = fdot2f(CA, X3, A6);   A7  = fdot2f(CO, X4, A7);                        \
    A8  = fdot2f(CA, X4, A8);   A9  = fdot2f(CO, X5, A9);                        \
    A10 = fdot2f(CA, X5, A10);  A11 = fdot2f(CO, X6, A11);                       \
    A12 = fdot2f(CA, X6, A12);  A13 = fdot2f(CO, X7, A13);                       \
    A14 = fdot2f(CA, X7, A14);  A15 = fdot2f(CO, X8, A15);

#define DO_BLOCK(B, p0_,p1_,p2_,p3_,p4_,p5_,p6_,p7_,p8_,p9_,p10_,p11_,p12_,p13_,p14_,p15_,p16_,p17_,p18_,p19_) \
    {                                                                             \
        const unsigned int ca0 = cvq.x, ca1 = cvq.y, ca2 = cvq.z, ca3 = cvq.w;    \
        uint4 ncq, nwq; unsigned int c8v = 0;                                     \
        if ((B) < 7) {                                                            \
            ncq = *(const uint4*)(SHu + cb + 4 * (B) + 4);                        \
            nwq = *(const uint4*)(SHu + SLOTU(W0u + 20 + 4 * (B)));               \
        } else {                                                                  \
            c8v = SHu[cb + 36];                                                   \
        }                                                                         \
        const unsigned int co0 = AB(ca1, ca0);                                    \
        const unsigned int co1 = AB(ca2, ca1);                                    \
        const unsigned int co2 = AB(ca3, ca2);                                    \
        const unsigned int co3 = AB(((B) < 7) ? ncq.x : c8v, ca3);                \
        PSTEP(ca0, co0, p0_, p1_, p2_, p3_, p4_, p5_, p6_, p7_, p8_)              \
        PSTEP(ca1, co1, p1_, p2_, p3_, p4_, p5_, p6_, p7_, p8_, p9_)              \
        PSTEP(ca2, co2, p2_, p3_, p4_, p5_, p6_, p7_, p8_, p9_, p10_)             \
        PSTEP(ca3, co3, p3_, p4_, p5_, p6_, p7_, p8_, p9_, p10_, p11_)            \
        if ((B) < 7) {                                                            \
            p16_ = nwq.x; p17_ = nwq.y; p18_ = nwq.z; p19_ = nwq.w;               \
            cvq = ncq;                                                            \
        }                                                                         \
    }

    DO_BLOCK(0, aw0,aw1,aw2,aw3,aw4,aw5,aw6,aw7,aw8,aw9,aw10,aw11,aw12,aw13,aw14,aw15,aw16,aw17,aw18,aw19)
    DO_BLOCK(1, aw4,aw5,aw6,aw7,aw8,aw9,aw10,aw11,aw12,aw13,aw14,aw15,aw16,aw17,aw18,aw19,aw0,aw1,aw2,aw3)
    DO_BLOCK(2, aw8,aw9,aw10,aw11,aw12,aw13,aw14,aw15,aw16,aw17,aw18,aw19,aw0,aw1,aw2,aw3,aw4,aw5,aw6,aw7)
    DO_BLOCK(3, aw12,aw13,aw14,aw15,aw16,aw17,aw18,aw19,aw0,aw1,aw2,aw3,aw4,aw5,aw6,aw7,aw8,aw9,aw10,aw11)
    DO_BLOCK(4, aw16,aw17,aw18,aw19,aw0,aw1,aw2,aw3,aw4,aw5,aw6,aw7,aw8,aw9,aw10,aw11,aw12,aw13,aw14,aw15)
    DO_BLOCK(5, aw0,aw1,aw2,aw3,aw4,aw5,aw6,aw7,aw8,aw9,aw10,aw11,aw12,aw13,aw14,aw15,aw16,aw17,aw18,aw19)
    DO_BLOCK(6, aw4,aw5,aw6,aw7,aw8,aw9,aw10,aw11,aw12,aw13,aw14,aw15,aw16,aw17,aw18,aw19,aw0,aw1,aw2,aw3)
    DO_BLOCK(7, aw8,aw9,aw10,aw11,aw12,aw13,aw14,aw15,aw16,aw17,aw18,aw19,aw0,aw1,aw2,aw3,aw4,aw5,aw6,aw7)
#undef DO_BLOCK
#undef PSTEP

    // ---------------- phase 4: reduce partials over g ----------------------------
    // Pre-reduce g pairs in registers (g <-> g^2), then 2-group LDS roundtrip.
#define RED32(K) A##K += __shfl_xor(A##K, 32);
    RED32(0)  RED32(1)  RED32(2)  RED32(3)  RED32(4)  RED32(5)  RED32(6)  RED32(7)
    RED32(8)  RED32(9)  RED32(10) RED32(11) RED32(12) RED32(13) RED32(14) RED32(15)
#undef RED32
    if (lane < 32) {                      // gg = g&1 in {0,1}
        const int gg = lane >> 4;
        const int iw = lane & 15;
        float4 v4;
        v4.x = A0;  v4.y = A1;  v4.z = A2;  v4.w = A3;
        *(float4*)(SB + 4 * PCHUNK2(gg, 0, iw)) = v4;
        v4.x = A4;  v4.y = A5;  v4.z = A6;  v4.w = A7;
        *(float4*)(SB + 4 * PCHUNK2(gg, 1, iw)) = v4;
        v4.x = A8;  v4.y = A9;  v4.z = A10; v4.w = A11;
        *(float4*)(SB + 4 * PCHUNK2(gg, 2, iw)) = v4;
        v4.x = A12; v4.y = A13; v4.z = A14; v4.w = A15;
        *(float4*)(SB + 4 * PCHUNK2(gg, 3, iw)) = v4;
    }
    float a0, a1, a2, a3;
    {
        const int iio = lane >> 2, qo = lane & 3;
        float4 u0 = *(const float4*)(SB + 4 * PCHUNK2(0, qo, iio));
        float4 u1 = *(const float4*)(SB + 4 * PCHUNK2(1, qo, iio));
        a0 = u0.x + u1.x;
        a1 = u0.y + u1.y;
        a2 = u0.z + u1.z;
        a3 = u0.w + u1.w;
    }
    // lane now owns corr[4l..4l+3]

    // ---------------- phase 5: CMND (csv in regs, reversed cs from LDS) ----------
    float4 csr  = *(const float4*)(SB + CS_B + 252 - 4 * lane);
    float csTop = SB[CS_B + 256 - 4 * lane];

    float d0 = csTop - 2.0f * a0 + totE - csx;
    float d1 = csr.w - 2.0f * a1 + totE - csy;
    float d2 = csr.z - 2.0f * a2 + totE - csz;
    float d3 = csr.y - 2.0f * a3 + totE - csw_;
    if (lane == 0) d0 = 0.0f;                 // diff[0] excluded from prefix
    float l0 = d0, l1 = l0 + d1, l2 = l1 + d2, l3 = l2 + d3;
    float scn = wave_iscan_add(l3);
    float pb = scn - l3;
    const int gbase = 4 * lane;               // global tau idx of slot 0
    float cd0 = d0 * (float)(gbase + 0) * frcp(pb + l0 + 1e-7f);
    float cd1 = d1 * (float)(gbase + 1) * frcp(pb + l1 + 1e-7f);
    float cd2 = d2 * (float)(gbase + 2) * frcp(pb + l2 + 1e-7f);
    float cd3 = d3 * (float)(gbase + 3) * frcp(pb + l3 + 1e-7f);

    // ---------------- phase 6: threshold + tau, fully in registers ---------------
    // cmnd[i] = cd value at global idx g = i + 26; neighbors via 2 shfl.
    const float prev3 = __shfl_up(cd3, 1);    // value at g-1 (junk at lane0: masked)
    const float next0 = __shfl_down(cd0, 1);  // value at g+4 (junk at lane63: masked)

    int thr = 0, lmm = 0;
    float sh0 = 0.f, sh1 = 0.f, sh2 = 0.f, sh3 = 0.f;
#define SLOT(S, PP, CC, NN, SH)                                                  \
    {                                                                            \
        const int i = gbase + (S) - TAU_MINC;                                    \
        const bool val = (i >= 0) && (i < C_LEN);                                \
        if (val && (CC) < 0.1f) thr |= (1 << (S));                               \
        const bool Lc = (i == 0) || ((CC) - (PP) <= 0.0f);                       \
        const bool Rc = (i == C_LEN - 1) || ((NN) - (CC) >= 0.0f);               \
        if (val && Lc && Rc) lmm |= (1 << (S));                                  \
        if (i >= 1 && i <= C_LEN - 2) {                                          \
            const float aa = (NN) + (PP) - 2.0f * (CC);                          \
            const float bb = 0.5f * ((NN) - (PP));                               \
            SH = (fabsf(bb) >= fabsf(aa)) ? 0.0f : (-bb / aa);                   \
        }                                                                        \
    }
    SLOT(0, prev3, cd0, cd1, sh0)
    SLOT(1, cd0,   cd1, cd2, sh1)
    SLOT(2, cd1,   cd2, cd3, sh2)
    SLOT(3, cd2,   cd3, next0, sh3)
#undef SLOT

    unsigned long long bt = __ballot(thr != 0);
    int thold = C_LEN;
    if (bt != 0ULL) {
        const int Lw = __ffsll(bt) - 1;
        const int bits = __builtin_amdgcn_readlane(thr, Lw);
        const int ifirst = 4 * Lw + (__ffs(bits) - 1) - TAU_MINC;
        thold = (ifirst == 0) ? C_LEN : ifirst;
    }

    int lm2 = lmm;
    const int gmin = thold + TAU_MINC;
    if (gbase + 3 < gmin) lm2 = 0;
    else if (gbase < gmin) lm2 &= ~((1 << (gmin - gbase)) - 1);
    unsigned long long bl = __ballot(lm2 != 0);
    int tau = 0;
    if (bl != 0ULL) {
        const int Lw2 = __ffsll(bl) - 1;
        const int bits2 = __builtin_amdgcn_readlane(lm2, Lw2);
        tau = 4 * Lw2 + (__ffs(bits2) - 1) - TAU_MINC;
    }

    // ---------------- phase 7: parabolic interp + pitch --------------------------
    float pv = 0.0f;
    if (tau > 0) {                             // wave-uniform
        const int gt = tau + TAU_MINC;
        const int ln = gt >> 2, sl = gt & 3;
        float shsel = (sl == 0) ? sh0 : (sl == 1) ? sh1 : (sl == 2) ? sh2 : sh3;
        const float shift = __shfl(shsel, ln);
        pv = 16000.0f / ((float)(gt + 1) + shift);
    }
    if (lane == 0) pitch[frame] = pv;
}

// 30-wide median (index 14 of ascending sort), edge-padded (15,14).
// Fully unrolled selection so v[] stays in registers.
__global__ __launch_bounds__(256) void median_k(const float* __restrict__ pitch,
                                                float* __restrict__ out) {
    int idx = blockIdx.x * blockDim.x + threadIdx.x;
    if (idx >= NFRAMES) return;
    int b = idx / NF;
    int f = idx - b * NF;
    const float* p = pitch + b * NF;
    float v[30];
#pragma unroll
    for (int k = 0; k < 30; ++k) {
        int j = f + k - 15;
        j = (j < 0) ? 0 : ((j > NF - 1) ? NF - 1 : j);
        v[k] = p[j];
    }
    float result = 0.0f;
#pragma unroll
    for (int i = 0; i < 30; ++i) {
        int lt = 0, le = 0;
#pragma unroll
        for (int j = 0; j < 30; ++j) {
            lt += (v[j] < v[i]);
            le += (v[j] <= v[i]);
        }
        if (lt <= 14 && 14 < le) result = v[i];
    }
    out[idx] = result;
}

extern "C" void kernel_launch(void* const* d_in, const int* in_sizes, int n_in,
                              void* d_out, int out_size, void* d_ws, size_t ws_size,
                              hipStream_t stream) {
    (void)in_sizes; (void)n_in; (void)out_size; (void)ws_size;
    const float* in = (const float*)d_in[0];
    float* out = (float*)d_out;
    float* pitch = (float*)d_ws;     // NFRAMES floats = 256 KB scratch

    yin_frames<<<NFRAMES / 2, 128, 0, stream>>>(in, pitch);
    median_k<<<(NFRAMES + 255) / 256, 256, 0, stream>>>(pitch, out);
}

// Round 11
// 73.550 us; speedup vs baseline: 1.5533x; 1.5533x over previous
//
#include <hip/hip_runtime.h>
#include <math.h>

// YIN pitch, MI355X. Constants from reference:
//   SR=16000, STRIDES=160, W=257, TAU_MAX=213, TAU_MIN=26, C=187, MEDIAN=30
#define T_LEN    160000
#define STRIDES  160
#define NF       1001
#define NB       64
#define TAU_MINC 26
#define C_LEN    187
#define NFRAMES  (NB * NF)     // 64064

// ---- Per-wave LDS map (u32 units) -------------------------------------------
// A copies: copy c in [0,8) at half base C0(c)=313c; x_ext[j] lives at half
//   S_c + j, S_c = 313c+16 (so S_c == c mod 8 -> every A-frag read is an
//   aligned b128), j in [-16,288). Halfs [0,2495).
// B: u32 base BBU; word w in [0,264) at BBU+SLOTU(w) (pad per 32 u32 kills the
//   8n-stride conflicts; keeps b128 alignment since pads are quad-multiples).
// cs: float base CSB, 257 floats. D-transpose floats [0,288) and CM floats
//   [288,504) alias the dead A region after the MFMA chain.
#define WAVE_U32 1804
#define BBU      1248
#define CSB      1544
#define DTB      0
#define CMB      288
#define SLOTU(U) ((U) + 4 * ((U) >> 5))

typedef __fp16 half2_t __attribute__((ext_vector_type(2)));
typedef __fp16 f16x8   __attribute__((ext_vector_type(8)));
typedef float  f32x4   __attribute__((ext_vector_type(4)));
union H2U  { half2_t h; unsigned int u; };
union U4H8 { uint4 u; f16x8 h; };

__device__ __forceinline__ unsigned int pack2h(float a, float b) {
    H2U x;
#if __has_builtin(__builtin_amdgcn_cvt_pkrtz)
    x.h = __builtin_amdgcn_cvt_pkrtz(a, b);
#else
    x.h.x = (__fp16)a; x.h.y = (__fp16)b;
#endif
    return x.u;
}
__device__ __forceinline__ float frcp(float x) {
#if __has_builtin(__builtin_amdgcn_rcpf)
    return __builtin_amdgcn_rcpf(x);
#else
    return 1.0f / x;
#endif
}

// R2-R4 lesson: arrays with computed indices survive SROA as allocas ->
// scratch -> 6 GB HBM. Named scalars / const-indexed vectors only.

__global__ __launch_bounds__(128, 5) void yin_frames(const float* __restrict__ in,
                                                     float* __restrict__ pitch) {
    __shared__ __align__(16) unsigned int SB_[2][WAVE_U32];

    const int wid  = threadIdx.x >> 6;
    const int lane = threadIdx.x & 63;
    const int frame = blockIdx.x * 2 + wid;
    const int b = frame / NF;
    const int f = frame - b * NF;
    unsigned int* SHu = SB_[wid];
    float* SBf = (float*)SHu;

    // ---------------- phase 0: zero the whole A+B region -------------------------
    {
        uint4 z; z.x = 0u; z.y = 0u; z.z = 0u; z.w = 0u;
#pragma unroll
        for (int k = 0; k < 6; ++k) *(uint4*)(SHu + 4 * lane + 256 * k) = z;
        if (lane < 8) SHu[1536 + lane] = 0u;    // u32 [1536,1544)
    }

    // ---------------- phase 1: load frame + build packed variants ----------------
    const float* src = in + (size_t)b * T_LEN;
    const int start = f * STRIDES;
    int e0i = start + 4 * lane;
    float4 q;
    if (e0i + 3 < T_LEN) {
        q = *(const float4*)(src + e0i);
    } else {
        q.x = (e0i + 0 < T_LEN) ? src[e0i + 0] : 0.f;
        q.y = (e0i + 1 < T_LEN) ? src[e0i + 1] : 0.f;
        q.z = (e0i + 2 < T_LEN) ? src[e0i + 2] : 0.f;
        q.w = (e0i + 3 < T_LEN) ? src[e0i + 3] : 0.f;
    }
    float s256f = 0.0f;
    if (lane == 0) {
        int e2 = start + 256;
        s256f = (e2 < T_LEN) ? src[e2] : 0.f;
    }
    s256f = __shfl(s256f, 0);

    unsigned int e0 = pack2h(q.x, q.y), e1 = pack2h(q.z, q.w);
    float prevw = __shfl_up(q.w, 1); if (lane == 0) prevw = 0.f;
    unsigned int o0 = pack2h(prevw, q.x), o1 = pack2h(q.y, q.z);
    unsigned int e1p = __shfl_up(e1, 1); if (lane == 0) e1p = 0u;  // x[4l-2],x[4l-1]
    unsigned int o1p = __shfl_up(o1, 1); if (lane == 0) o1p = 0u;  // x[4l-3],x[4l-2]
    const float x253 = __shfl(q.y, 63);
    const float x254 = __shfl(q.z, 63);
    const float x255 = __shfl(q.w, 63);

    // A copies (8, shifted) + B. Variant bases: (S_c + shift)/2 precomputed,
    // all even (uint2-aligned). Data invariant: x_ext[j] at half S_c + j.
    { uint2 d; d.x = e0;  d.y = e1;                      // c=0 (S=16), c=4 (S=1268)
      *(uint2*)(SHu + 8    + 2 * lane) = d;
      *(uint2*)(SHu + 634  + 2 * lane) = d;
      *(uint2*)(SHu + BBU + SLOTU(2 * lane)) = d; }      // B words 2l,2l+1
    { uint2 d; d.x = o0;  d.y = o1;                      // c=1 (S=329), c=5 (S=1581)
      *(uint2*)(SHu + 164  + 2 * lane) = d;
      *(uint2*)(SHu + 790  + 2 * lane) = d; }
    { uint2 d; d.x = e1p; d.y = e0;                      // c=2 (S=642), c=6 (S=1894)
      *(uint2*)(SHu + 320  + 2 * lane) = d;
      *(uint2*)(SHu + 946  + 2 * lane) = d; }
    { uint2 d; d.x = o1p; d.y = o0;                      // c=3 (S=955), c=7 (S=2207)
      *(uint2*)(SHu + 476  + 2 * lane) = d;
      *(uint2*)(SHu + 1102 + 2 * lane) = d; }
    if (lane == 0) {                                     // tail patches x253..x256
        unsigned int p256   = pack2h(s256f, 0.f);
        unsigned int p55_56 = pack2h(x255, s256f);
        unsigned int p54_55 = pack2h(x254, x255);
        unsigned int p53_54 = pack2h(x253, x254);
        SHu[136] = p256;  SHu[762] = p256;               // c0,c4: half S+256
        SHu[292] = p55_56; SHu[918] = p55_56;            // c1,c5: halfs S+255,256
        { uint2 d; d.x = p54_55; d.y = p256;
          *(uint2*)(SHu + 448)  = d; *(uint2*)(SHu + 1074) = d; }  // c2,c6: S+254..257
        { uint2 d; d.x = p53_54; d.y = p55_56;
          *(uint2*)(SHu + 604)  = d; *(uint2*)(SHu + 1230) = d; }  // c3,c7: S+253..256
        SHu[1392] = p256;                                // B word 128 (halfs 256,257)
    }

    // ---------------- phase 2: cumsum of squares (fp32, wave scan) ---------------
    float p0 = q.x * q.x;
    float p1 = p0 + q.y * q.y;
    float p2 = p1 + q.z * q.z;
    float p3 = p2 + q.w * q.w;
    float sc = p3;
#pragma unroll
    for (int off = 1; off < 64; off <<= 1) {
        float o = __shfl_up(sc, off);
        if (lane >= off) sc += o;
    }
    const float csbase = sc - p3;
    const float csx = csbase + p0, csy = csbase + p1, csz = csbase + p2, csw_ = csbase + p3;
    {
        float4 c4; c4.x = csx; c4.y = csy; c4.z = csz; c4.w = csw_;
        *(float4*)(SBf + CSB + 4 * lane) = c4;          // for reversed reads
    }
    float totE = __shfl(sc, 63) + s256f * s256f;
    if (lane == 63) SBf[CSB + 256] = totE;

    // ---------------- phase 3: autocorr via 9x mfma_f32_16x16x32_f16 -------------
    // A[m][k] = x_ext[k-m] (lane m+16kb reads 8 halfs, aligned via copy c=m&7);
    // B[k][n] = x[k+16n]; D[m][n] = corr[16n+m]. Both frags use the same k
    // convention, so any HW k-permutation cancels. C/D layout per m89.
    const int m  = lane & 15;
    const int kb = lane >> 4;
    const int cA = m & 7, tA = m >> 3;
    const int au_base = 156 * cA + 8 - 4 * tA + 4 * kb;  // u32, ==0 mod 4
    const int wbase = 4 * kb + 8 * m;                    // B word base (n == m)

    f32x4 acc = {0.f, 0.f, 0.f, 0.f};
#define MSTEP(KK)                                                                \
    {                                                                            \
        U4H8 ua, ub;                                                             \
        ua.u = *(const uint4*)(SHu + au_base + 16 * (KK));                       \
        const int w_ = wbase + 16 * (KK);                                        \
        ub.u = *(const uint4*)(SHu + BBU + w_ + 4 * (w_ >> 5));                  \
        acc = __builtin_amdgcn_mfma_f32_16x16x32_f16(ua.h, ub.h, acc, 0, 0, 0);  \
    }
    MSTEP(0) MSTEP(1) MSTEP(2) MSTEP(3) MSTEP(4)
    MSTEP(5) MSTEP(6) MSTEP(7) MSTEP(8)
#undef MSTEP

    // ---------------- phase 4: transpose D -> lane j owns corr[4j..4j+3] ---------
    // lane l, reg r holds corr[16(l&15)+4(l>>4)+r] = corr[4*jj+r], jj=4m+kb.
    {
        const int jj = 4 * m + kb;
        float4 av; av.x = acc[0]; av.y = acc[1]; av.z = acc[2]; av.w = acc[3];
        *(float4*)(SBf + DTB + 4 * jj + 4 * (jj >> 3)) = av;   // pad: conflict-free
    }
    float a0, a1, a2, a3;
    {
        const int rb = 4 * lane + 4 * (lane >> 3);
        float4 cr = *(const float4*)(SBf + DTB + rb);
        a0 = cr.x; a1 = cr.y; a2 = cr.z; a3 = cr.w;
    }

    // ---------------- phase 5: CMND (R9-proven) ----------------------------------
    float4 csr  = *(const float4*)(SBf + CSB + 252 - 4 * lane);
    float csTop = SBf[CSB + 256 - 4 * lane];

    float d0 = csTop - 2.0f * a0 + totE - csx;
    float d1 = csr.w - 2.0f * a1 + totE - csy;
    float d2 = csr.z - 2.0f * a2 + totE - csz;
    float d3 = csr.y - 2.0f * a3 + totE - csw_;
    if (lane == 0) d0 = 0.0f;                 // diff[0] excluded from prefix
    float l0 = d0, l1 = l0 + d1, l2 = l1 + d2, l3 = l2 + d3;
    float scn = l3;
#pragma unroll
    for (int off = 1; off < 64; off <<= 1) {
        float o = __shfl_up(scn, off);
        if (lane >= off) scn += o;
    }
    float pb = scn - l3;
    const int t0 = 4 * lane;
    float cd0 = d0 * (float)(t0 + 0) * frcp(pb + l0 + 1e-7f);
    float cd1 = d1 * (float)(t0 + 1) * frcp(pb + l1 + 1e-7f);
    float cd2 = d2 * (float)(t0 + 2) * frcp(pb + l2 + 1e-7f);
    float cd3 = d3 * (float)(t0 + 3) * frcp(pb + l3 + 1e-7f);
    if (lane <= 53) {                          // taus 0..215 (>=213 junk, never used)
        float4 cdv;
        cdv.x = (lane == 0) ? 1.0f : cd0;
        cdv.y = cd1; cdv.z = cd2; cdv.w = cd3;
        *(float4*)(SBf + CMB + t0) = cdv;
    }

    // ---------------- phase 6: threshold + tau searches via ballot (R9) ----------
    const float am0 = SBf[CMB + 25 + lane];
    const float bm0 = SBf[CMB + 26 + lane];
    const float cn0 = SBf[CMB + 27 + lane];
    const float am1 = SBf[CMB + 25 + 64 + lane];
    const float bm1 = SBf[CMB + 26 + 64 + lane];
    const float cn1 = SBf[CMB + 27 + 64 + lane];
    const float am2 = SBf[CMB + 25 + 128 + lane];
    const float bm2 = SBf[CMB + 26 + 128 + lane];
    const float cn2 = SBf[CMB + 27 + 128 + lane];

    unsigned long long tm0 = __ballot((lane < 187)       && (bm0 < 0.1f));
    unsigned long long tm1 = __ballot((64 + lane < 187)  && (bm1 < 0.1f));
    unsigned long long tm2 = __ballot((128 + lane < 187) && (bm2 < 0.1f));
    int cand = tm0 ? (__ffsll(tm0) - 1)
             : (tm1 ? (64 + __ffsll(tm1) - 1)
             : (tm2 ? (128 + __ffsll(tm2) - 1) : 999));
    const int thold = (cand == 0 || cand == 999) ? C_LEN : cand;

    const int i0 = lane, i1 = 64 + lane, i2 = 128 + lane;
    bool L0 = (i0 == 0)   || (bm0 - am0 <= 0.0f);
    bool R0 = (i0 == 186) || (cn0 - bm0 >= 0.0f);
    bool L1 = (bm1 - am1 <= 0.0f);
    bool R1 = (cn1 - bm1 >= 0.0f);
    bool L2 = (bm2 - am2 <= 0.0f);
    bool R2 = (i2 == 186) || (cn2 - bm2 >= 0.0f);
    unsigned long long lm0 = __ballot((i0 >= thold) && (i0 < C_LEN) && L0 && R0);
    unsigned long long lm1 = __ballot((i1 >= thold) && (i1 < C_LEN) && L1 && R1);
    unsigned long long lm2 = __ballot((i2 >= thold) && (i2 < C_LEN) && L2 && R2);
    int tcand = lm0 ? (__ffsll(lm0) - 1)
              : (lm1 ? (64 + __ffsll(lm1) - 1)
              : (lm2 ? (128 + __ffsll(lm2) - 1) : 999));
    const int tau = (tcand == 999) ? 0 : tcand;

    // ---------------- phase 7: parabolic interp + pitch --------------------------
    float pv = 0.0f;
    if (tau > 0) {
        float shift = 0.0f;
        if (tau <= C_LEN - 2) {
            float pp = SBf[CMB + 26 + tau - 1];
            float cc = SBf[CMB + 26 + tau];
            float nn = SBf[CMB + 26 + tau + 1];
            float aa = nn + pp - 2.0f * cc;
            float bb = 0.5f * (nn - pp);
            shift = (fabsf(bb) >= fabsf(aa)) ? 0.0f : (-bb / aa);
        }
        pv = 16000.0f / ((float)(tau + TAU_MINC + 1) + shift);
    }
    if (lane == 0) pitch[frame] = pv;
}

// 30-wide median (index 14 of ascending sort), edge-padded (15,14).
// Fully unrolled selection so v[] stays in registers.
__global__ __launch_bounds__(256) void median_k(const float* __restrict__ pitch,
                                                float* __restrict__ out) {
    int idx = blockIdx.x * blockDim.x + threadIdx.x;
    if (idx >= NFRAMES) return;
    int b = idx / NF;
    int f = idx - b * NF;
    const float* p = pitch + b * NF;
    float v[30];
#pragma unroll
    for (int k = 0; k < 30; ++k) {
        int j = f + k - 15;
        j = (j < 0) ? 0 : ((j > NF - 1) ? NF - 1 : j);
        v[k] = p[j];
    }
    float result = 0.0f;
#pragma unroll
    for (int i = 0; i < 30; ++i) {
        int lt = 0, le = 0;
#pragma unroll
        for (int j = 0; j < 30; ++j) {
            lt += (v[j] < v[i]);
            le += (v[j] <= v[i]);
        }
        if (lt <= 14 && 14 < le) result = v[i];
    }
    out[idx] = result;
}

extern "C" void kernel_launch(void* const* d_in, const int* in_sizes, int n_in,
                              void* d_out, int out_size, void* d_ws, size_t ws_size,
                              hipStream_t stream) {
    (void)in_sizes; (void)n_in; (void)out_size; (void)ws_size;
    const float* in = (const float*)d_in[0];
    float* out = (float*)d_out;
    float* pitch = (float*)d_ws;     // NFRAMES floats = 256 KB scratch

    yin_frames<<<NFRAMES / 2, 128, 0, stream>>>(in, pitch);
    median_k<<<(NFRAMES + 255) / 256, 256, 0, stream>>>(pitch, out);
}

// Round 12
// 63.862 us; speedup vs baseline: 1.7890x; 1.1517x over previous
//
#include <hip/hip_runtime.h>
#include <math.h>

// YIN pitch, MI355X. Constants from reference:
//   SR=16000, STRIDES=160, W=257, TAU_MAX=213, TAU_MIN=26, C=187, MEDIAN=30
#define T_LEN    160000
#define STRIDES  160
#define NF       1001
#define NB       64
#define TAU_MINC 26
#define C_LEN    187
#define NFRAMES  (NB * NF)     // 64064
#define GRIDB    2304          // 9 blocks/CU x 256 CU; ~14 frames per wave

// ---- Per-wave LDS map (u32 units) -------------------------------------------
// A copies: copy c in [0,8) at half base 313c; x_ext[j] at half S_c + j,
//   S_c = 313c+16 (S_c == c mod 8 -> every A-frag read is an aligned b128).
// B: u32 base BBU; word w at BBU+SLOTU(w).  [0,1544) zeroed ONCE (pads/tails
//   never rewritten; per-frame staging + patches cover exactly the live words).
// CS: floats [1544,1801). DT (D transpose): floats [1804,2088) - DEDICATED
//   (no aliasing over A, so zero-once survives the persistent loop).
#define WAVE_U32 2088
#define BBU      1248
#define CSB      1544
#define DTB      1804
#define SLOTU(U) ((U) + 4 * ((U) >> 5))

typedef __fp16 half2_t __attribute__((ext_vector_type(2)));
typedef __fp16 f16x8   __attribute__((ext_vector_type(8)));
typedef float  f32x4   __attribute__((ext_vector_type(4)));
union H2U  { half2_t h; unsigned int u; };
union U4H8 { uint4 u; f16x8 h; };

__device__ __forceinline__ unsigned int pack2h(float a, float b) {
    H2U x;
#if __has_builtin(__builtin_amdgcn_cvt_pkrtz)
    x.h = __builtin_amdgcn_cvt_pkrtz(a, b);
#else
    x.h.x = (__fp16)a; x.h.y = (__fp16)b;
#endif
    return x.u;
}
__device__ __forceinline__ float frcp(float x) {
#if __has_builtin(__builtin_amdgcn_rcpf)
    return __builtin_amdgcn_rcpf(x);
#else
    return 1.0f / x;
#endif
}

// ---- DPP wave-inclusive scan (VALU pipe, no LDS) - R10-proven ----------------
template<int CTRL, int RMASK, bool BC>
__device__ __forceinline__ float dpp_add(float v) {
    union { float f; int i; } a, r;
    a.f = v;
    r.i = __builtin_amdgcn_update_dpp(0, a.i, CTRL, RMASK, 0xF, BC);
    return v + r.f;
}
__device__ __forceinline__ float wave_iscan_add(float x) {
    float v = x;
    v = dpp_add<0x111, 0xF, true>(v);    // row_shr:1
    v = dpp_add<0x112, 0xF, true>(v);    // row_shr:2
    v = dpp_add<0x114, 0xF, true>(v);    // row_shr:4
    v = dpp_add<0x118, 0xF, true>(v);    // row_shr:8
    v = dpp_add<0x142, 0xA, false>(v);   // row_bcast:15 -> rows 1,3
    v = dpp_add<0x143, 0xC, false>(v);   // row_bcast:31 -> rows 2,3
    return v;
}

// R2-R4 lesson: arrays with computed indices survive SROA as allocas ->
// scratch -> 6 GB HBM. Named scalars / const-indexed vectors only.

__global__ __launch_bounds__(128, 4) void yin_frames(const float* __restrict__ in,
                                                     float* __restrict__ pitch) {
    __shared__ __align__(16) unsigned int SB_[2][WAVE_U32];

    const int wid  = threadIdx.x >> 6;
    const int lane = threadIdx.x & 63;
    unsigned int* SHu = SB_[wid];
    float* SBf = (float*)SHu;

    // ---------------- zero-once: whole A+B region [0,1544) -----------------------
    {
        uint4 z; z.x = 0u; z.y = 0u; z.z = 0u; z.w = 0u;
#pragma unroll
        for (int k = 0; k < 6; ++k) *(uint4*)(SHu + 4 * lane + 256 * k) = z;
        if (lane < 2) *(uint4*)(SHu + 1536 + 4 * lane) = z;   // u32 [1536,1544)
    }

    const int fstride = GRIDB * 2;
    for (int frame = blockIdx.x * 2 + wid; frame < NFRAMES; frame += fstride) {
    const int b = frame / NF;
    const int f = frame - b * NF;

    // ---------------- phase 1: load frame + build packed variants ----------------
    const float* src = in + (size_t)b * T_LEN;
    const int start = f * STRIDES;
    int e0i = start + 4 * lane;
    float4 q;
    if (e0i + 3 < T_LEN) {
        q = *(const float4*)(src + e0i);
    } else {
        q.x = (e0i + 0 < T_LEN) ? src[e0i + 0] : 0.f;
        q.y = (e0i + 1 < T_LEN) ? src[e0i + 1] : 0.f;
        q.z = (e0i + 2 < T_LEN) ? src[e0i + 2] : 0.f;
        q.w = (e0i + 3 < T_LEN) ? src[e0i + 3] : 0.f;
    }
    float s256f = 0.0f;
    if (lane == 0) {
        int e2 = start + 256;
        s256f = (e2 < T_LEN) ? src[e2] : 0.f;
    }
    s256f = __shfl(s256f, 0);

    unsigned int e0 = pack2h(q.x, q.y), e1 = pack2h(q.z, q.w);
    float prevw = __shfl_up(q.w, 1); if (lane == 0) prevw = 0.f;
    unsigned int o0 = pack2h(prevw, q.x), o1 = pack2h(q.y, q.z);
    unsigned int e1p = __shfl_up(e1, 1); if (lane == 0) e1p = 0u;  // x[4l-2],x[4l-1]
    unsigned int o1p = __shfl_up(o1, 1); if (lane == 0) o1p = 0u;  // x[4l-3],x[4l-2]
    const float x253 = __shfl(q.y, 63);
    const float x254 = __shfl(q.z, 63);
    const float x255 = __shfl(q.w, 63);

    // A copies (8, shifted) + B: R11-proven bases. x_ext[j] at half S_c + j.
    { uint2 d; d.x = e0;  d.y = e1;                      // c=0 (S=16), c=4 (S=1268)
      *(uint2*)(SHu + 8    + 2 * lane) = d;
      *(uint2*)(SHu + 634  + 2 * lane) = d;
      *(uint2*)(SHu + BBU + SLOTU(2 * lane)) = d; }      // B words 2l,2l+1
    { uint2 d; d.x = o0;  d.y = o1;                      // c=1 (S=329), c=5 (S=1581)
      *(uint2*)(SHu + 164  + 2 * lane) = d;
      *(uint2*)(SHu + 790  + 2 * lane) = d; }
    { uint2 d; d.x = e1p; d.y = e0;                      // c=2 (S=642), c=6 (S=1894)
      *(uint2*)(SHu + 320  + 2 * lane) = d;
      *(uint2*)(SHu + 946  + 2 * lane) = d; }
    { uint2 d; d.x = o1p; d.y = o0;                      // c=3 (S=955), c=7 (S=2207)
      *(uint2*)(SHu + 476  + 2 * lane) = d;
      *(uint2*)(SHu + 1102 + 2 * lane) = d; }
    {   // tail patches x253..x256: 13 u32 writes distributed over lanes 0-12
        unsigned int p256   = pack2h(s256f, 0.f);
        unsigned int p55_56 = pack2h(x255, s256f);
        unsigned int p54_55 = pack2h(x254, x255);
        unsigned int p53_54 = pack2h(x253, x254);
        if (lane < 13) {
            int adr = (lane == 0)  ? 136  : (lane == 1)  ? 762  :
                      (lane == 2)  ? 292  : (lane == 3)  ? 918  :
                      (lane == 4)  ? 448  : (lane == 5)  ? 449  :
                      (lane == 6)  ? 1074 : (lane == 7)  ? 1075 :
                      (lane == 8)  ? 604  : (lane == 9)  ? 605  :
                      (lane == 10) ? 1230 : (lane == 11) ? 1231 : 1392;
            unsigned int pvv =
                (lane == 0 || lane == 1 || lane == 5 || lane == 7 || lane == 12) ? p256 :
                (lane == 2 || lane == 3 || lane == 9 || lane == 11) ? p55_56 :
                (lane == 4 || lane == 6) ? p54_55 : p53_54;
            SHu[adr] = pvv;
        }
    }

    // ---------------- phase 2: cumsum of squares (fp32, DPP scan) ----------------
    float p0 = q.x * q.x;
    float p1 = p0 + q.y * q.y;
    float p2 = p1 + q.z * q.z;
    float p3 = p2 + q.w * q.w;
    float sc = wave_iscan_add(p3);
    const float csbase = sc - p3;
    const float csx = csbase + p0, csy = csbase + p1, csz = csbase + p2, csw_ = csbase + p3;
    {
        float4 c4; c4.x = csx; c4.y = csy; c4.z = csz; c4.w = csw_;
        *(float4*)(SBf + CSB + 4 * lane) = c4;          // for reversed reads
    }
    float totE = __shfl(sc, 63) + s256f * s256f;
    if (lane == 63) SBf[CSB + 256] = totE;

    // ---------------- phase 3: autocorr via 9x mfma_f32_16x16x32_f16 -------------
    // A[m][k] = x_ext[k-m]; B[k][n] = x[k+16n]; D[m][n] = corr[16n+m]. R11-proven.
    const int m  = lane & 15;
    const int kb = lane >> 4;
    const int cA = m & 7, tA = m >> 3;
    const int au_base = 156 * cA + 8 - 4 * tA + 4 * kb;  // u32, ==0 mod 4
    const int wbase = 4 * kb + 8 * m;                    // B word base (n == m)

    f32x4 acc = {0.f, 0.f, 0.f, 0.f};
#define MSTEP(KK)                                                                \
    {                                                                            \
        U4H8 ua, ub;                                                             \
        ua.u = *(const uint4*)(SHu + au_base + 16 * (KK));                       \
        const int w_ = wbase + 16 * (KK);                                        \
        ub.u = *(const uint4*)(SHu + BBU + w_ + 4 * (w_ >> 5));                  \
        acc = __builtin_amdgcn_mfma_f32_16x16x32_f16(ua.h, ub.h, acc, 0, 0, 0);  \
    }
    MSTEP(0) MSTEP(1) MSTEP(2) MSTEP(3) MSTEP(4)
    MSTEP(5) MSTEP(6) MSTEP(7) MSTEP(8)
#undef MSTEP

    // ---------------- phase 4: transpose D -> lane j owns corr[4j..4j+3] ---------
    {
        const int jj = 4 * m + kb;
        float4 av; av.x = acc[0]; av.y = acc[1]; av.z = acc[2]; av.w = acc[3];
        *(float4*)(SBf + DTB + 4 * jj + 4 * (jj >> 3)) = av;   // pad: conflict-free
    }
    float a0, a1, a2, a3;
    {
        const int rb = 4 * lane + 4 * (lane >> 3);
        float4 cr = *(const float4*)(SBf + DTB + rb);
        a0 = cr.x; a1 = cr.y; a2 = cr.z; a3 = cr.w;
    }

    // ---------------- phase 5: CMND (DPP scan, cd in regs) -----------------------
    float4 csr  = *(const float4*)(SBf + CSB + 252 - 4 * lane);
    float csTop = SBf[CSB + 256 - 4 * lane];

    float d0 = csTop - 2.0f * a0 + totE - csx;
    float d1 = csr.w - 2.0f * a1 + totE - csy;
    float d2 = csr.z - 2.0f * a2 + totE - csz;
    float d3 = csr.y - 2.0f * a3 + totE - csw_;
    if (lane == 0) d0 = 0.0f;                 // diff[0] excluded from prefix
    float l0 = d0, l1 = l0 + d1, l2 = l1 + d2, l3 = l2 + d3;
    float scn = wave_iscan_add(l3);
    float pb = scn - l3;
    const int gbase = 4 * lane;               // global tau idx of slot 0
    float cd0 = d0 * (float)(gbase + 0) * frcp(pb + l0 + 1e-7f);
    float cd1 = d1 * (float)(gbase + 1) * frcp(pb + l1 + 1e-7f);
    float cd2 = d2 * (float)(gbase + 2) * frcp(pb + l2 + 1e-7f);
    float cd3 = d3 * (float)(gbase + 3) * frcp(pb + l3 + 1e-7f);

    // ---------------- phase 6: threshold + tau fully in registers (R10-proven) ---
    const float prev3 = __shfl_up(cd3, 1);    // value at g-1 (junk at lane0: masked)
    const float next0 = __shfl_down(cd0, 1);  // value at g+4 (junk at lane63: masked)

    int thr = 0, lmm = 0;
    float sh0 = 0.f, sh1 = 0.f, sh2 = 0.f, sh3 = 0.f;
#define SLOT(S, PP, CC, NN, SH)                                                  \
    {                                                                            \
        const int i = gbase + (S) - TAU_MINC;                                    \
        const bool val = (i >= 0) && (i < C_LEN);                                \
        if (val && (CC) < 0.1f) thr |= (1 << (S));                               \
        const bool Lc = (i == 0) || ((CC) - (PP) <= 0.0f);                       \
        const bool Rc = (i == C_LEN - 1) || ((NN) - (CC) >= 0.0f);               \
        if (val && Lc && Rc) lmm |= (1 << (S));                                  \
        if (i >= 1 && i <= C_LEN - 2) {                                          \
            const float aa = (NN) + (PP) - 2.0f * (CC);                          \
            const float bb = 0.5f * ((NN) - (PP));                               \
            SH = (fabsf(bb) >= fabsf(aa)) ? 0.0f : (-bb * frcp(aa));             \
        }                                                                        \
    }
    SLOT(0, prev3, cd0, cd1, sh0)
    SLOT(1, cd0,   cd1, cd2, sh1)
    SLOT(2, cd1,   cd2, cd3, sh2)
    SLOT(3, cd2,   cd3, next0, sh3)
#undef SLOT

    unsigned long long bt = __ballot(thr != 0);
    int thold = C_LEN;
    if (bt != 0ULL) {
        const int Lw = __ffsll(bt) - 1;
        const int bits = __builtin_amdgcn_readlane(thr, Lw);
        const int ifirst = 4 * Lw + (__ffs(bits) - 1) - TAU_MINC;
        thold = (ifirst == 0) ? C_LEN : ifirst;
    }

    int lm2 = lmm;
    const int gmin = thold + TAU_MINC;
    if (gbase + 3 < gmin) lm2 = 0;
    else if (gbase < gmin) lm2 &= ~((1 << (gmin - gbase)) - 1);
    unsigned long long bl = __ballot(lm2 != 0);
    int tau = 0;
    if (bl != 0ULL) {
        const int Lw2 = __ffsll(bl) - 1;
        const int bits2 = __builtin_amdgcn_readlane(lm2, Lw2);
        tau = 4 * Lw2 + (__ffs(bits2) - 1) - TAU_MINC;
    }

    // ---------------- phase 7: parabolic interp + pitch --------------------------
    float pv = 0.0f;
    if (tau > 0) {                             // wave-uniform
        const int gt = tau + TAU_MINC;
        const int ln = gt >> 2, sl = gt & 3;
        float shsel = (sl == 0) ? sh0 : (sl == 1) ? sh1 : (sl == 2) ? sh2 : sh3;
        const float shift = __shfl(shsel, ln);
        pv = 16000.0f / ((float)(gt + 1) + shift);
    }
    if (lane == 0) pitch[frame] = pv;

    }   // persistent frame loop
}

// 30-wide median (index 14 of ascending sort), edge-padded (15,14).
// Fully unrolled selection so v[] stays in registers.
__global__ __launch_bounds__(256) void median_k(const float* __restrict__ pitch,
                                                float* __restrict__ out) {
    int idx = blockIdx.x * blockDim.x + threadIdx.x;
    if (idx >= NFRAMES) return;
    int b = idx / NF;
    int f = idx - b * NF;
    const float* p = pitch + b * NF;
    float v[30];
#pragma unroll
    for (int k = 0; k < 30; ++k) {
        int j = f + k - 15;
        j = (j < 0) ? 0 : ((j > NF - 1) ? NF - 1 : j);
        v[k] = p[j];
    }
    float result = 0.0f;
#pragma unroll
    for (int i = 0; i < 30; ++i) {
        int lt = 0, le = 0;
#pragma unroll
        for (int j = 0; j < 30; ++j) {
            lt += (v[j] < v[i]);
            le += (v[j] <= v[i]);
        }
        if (lt <= 14 && 14 < le) result = v[i];
    }
    out[idx] = result;
}

extern "C" void kernel_launch(void* const* d_in, const int* in_sizes, int n_in,
                              void* d_out, int out_size, void* d_ws, size_t ws_size,
                              hipStream_t stream) {
    (void)in_sizes; (void)n_in; (void)out_size; (void)ws_size;
    const float* in = (const float*)d_in[0];
    float* out = (float*)d_out;
    float* pitch = (float*)d_ws;     // NFRAMES floats = 256 KB scratch

    yin_frames<<<GRIDB, 128, 0, stream>>>(in, pitch);
    median_k<<<(NFRAMES + 255) / 256, 256, 0, stream>>>(pitch, out);
}

// Round 13
// 52.146 us; speedup vs baseline: 2.1909x; 1.2247x over previous
//
#include <hip/hip_runtime.h>
#include <math.h>

// YIN pitch, MI355X. Constants from reference:
//   SR=16000, STRIDES=160, W=257, TAU_MAX=213, TAU_MIN=26, C=187, MEDIAN=30
#define T_LEN    160000
#define STRIDES  160
#define NF       1001
#define NB       64
#define TAU_MINC 26
#define C_LEN    187
#define NFRAMES  (NB * NF)     // 64064
#define GRIDB    3328          // 13 blocks/CU x 256 CU

// ---- Per-wave LDS map (u32 units) -------------------------------------------
// A: 4 shifted copies for b64 (8B) alignment classes mod 4. Copy c' base
//   P(c') = 8 + 168*c' (u32); x_ext[j] at half S+j, S = 2*P + c'.
//   P mod 32 = {8,16,24,0}: the 16 lanes' lo-banks form a PERMUTATION of the
//   16 even banks -> every bank exactly 2 accesses (b64 spans 2 banks) = free.
// B: base BBU2 == 2 mod 4 (prevents b128 re-merge); word w at
//   BBU2 + w + 2*(w>>3) -> per-16-lane banks 10m mod 32, all distinct.
// CS: floats [992,1249). DT: floats [1252,1536), dedicated.
#define WAVE_U32 1536
#define BBU2     662
#define CSB      992
#define DTB      1252

typedef __fp16 half2_t __attribute__((ext_vector_type(2)));
typedef __fp16 f16x8   __attribute__((ext_vector_type(8)));
typedef float  f32x4   __attribute__((ext_vector_type(4)));
union H2U  { half2_t h; unsigned int u; };
union U4H8 { uint4 u; f16x8 h; };

__device__ __forceinline__ unsigned int pack2h(float a, float b) {
    H2U x;
#if __has_builtin(__builtin_amdgcn_cvt_pkrtz)
    x.h = __builtin_amdgcn_cvt_pkrtz(a, b);
#else
    x.h.x = (__fp16)a; x.h.y = (__fp16)b;
#endif
    return x.u;
}
__device__ __forceinline__ float frcp(float x) {
#if __has_builtin(__builtin_amdgcn_rcpf)
    return __builtin_amdgcn_rcpf(x);
#else
    return 1.0f / x;
#endif
}

// ---- DPP wave-inclusive scan (VALU pipe, no LDS) - R10/R12-proven ------------
template<int CTRL, int RMASK, bool BC>
__device__ __forceinline__ float dpp_add(float v) {
    union { float f; int i; } a, r;
    a.f = v;
    r.i = __builtin_amdgcn_update_dpp(0, a.i, CTRL, RMASK, 0xF, BC);
    return v + r.f;
}
__device__ __forceinline__ float wave_iscan_add(float x) {
    float v = x;
    v = dpp_add<0x111, 0xF, true>(v);    // row_shr:1
    v = dpp_add<0x112, 0xF, true>(v);    // row_shr:2
    v = dpp_add<0x114, 0xF, true>(v);    // row_shr:4
    v = dpp_add<0x118, 0xF, true>(v);    // row_shr:8
    v = dpp_add<0x142, 0xA, false>(v);   // row_bcast:15 -> rows 1,3
    v = dpp_add<0x143, 0xC, false>(v);   // row_bcast:31 -> rows 2,3
    return v;
}

// R2-R4 lesson: arrays with computed indices survive SROA as allocas ->
// scratch -> 6 GB HBM. Named scalars / const-indexed vectors only.

__global__ __launch_bounds__(128, 6) void yin_frames(const float* __restrict__ in,
                                                     float* __restrict__ pitch) {
    __shared__ __align__(16) unsigned int SB_[2][WAVE_U32];

    const int wid  = threadIdx.x >> 6;
    const int lane = threadIdx.x & 63;
    unsigned int* SHu = SB_[wid];
    float* SBf = (float*)SHu;

    // ---------------- zero-once: A+B region [0,1024) (CS rewritten per frame) ----
    {
        uint4 z; z.x = 0u; z.y = 0u; z.z = 0u; z.w = 0u;
#pragma unroll
        for (int k = 0; k < 4; ++k) *(uint4*)(SHu + 4 * lane + 256 * k) = z;
    }

    const int fstride = GRIDB * 2;
    for (int frame = blockIdx.x * 2 + wid; frame < NFRAMES; frame += fstride) {
    const int b = frame / NF;
    const int f = frame - b * NF;

    // ---------------- phase 1: load frame + build packed variants ----------------
    const float* src = in + (size_t)b * T_LEN;
    const int start = f * STRIDES;
    int e0i = start + 4 * lane;
    float4 q;
    if (e0i + 3 < T_LEN) {
        q = *(const float4*)(src + e0i);
    } else {
        q.x = (e0i + 0 < T_LEN) ? src[e0i + 0] : 0.f;
        q.y = (e0i + 1 < T_LEN) ? src[e0i + 1] : 0.f;
        q.z = (e0i + 2 < T_LEN) ? src[e0i + 2] : 0.f;
        q.w = (e0i + 3 < T_LEN) ? src[e0i + 3] : 0.f;
    }
    float s256f = 0.0f;
    if (lane == 0) {
        int e2 = start + 256;
        s256f = (e2 < T_LEN) ? src[e2] : 0.f;
    }
    s256f = __shfl(s256f, 0);

    unsigned int e0 = pack2h(q.x, q.y), e1 = pack2h(q.z, q.w);
    float prevw = __shfl_up(q.w, 1); if (lane == 0) prevw = 0.f;
    unsigned int o0 = pack2h(prevw, q.x), o1 = pack2h(q.y, q.z);
    unsigned int e1p = __shfl_up(e1, 1); if (lane == 0) e1p = 0u;  // x[4l-2],x[4l-1]
    unsigned int o1p = __shfl_up(o1, 1); if (lane == 0) o1p = 0u;  // x[4l-3],x[4l-2]
    const float x253 = __shfl(q.y, 63);
    const float x254 = __shfl(q.z, 63);
    const float x255 = __shfl(q.w, 63);

    // A copies (4, shifted; bases 8,176,344,512) + B (padded w+2*(w>>3)).
    { uint2 d; d.x = e0;  d.y = e1;                      // c'=0: x[4l..4l+3]
      *(uint2*)(SHu + 8   + 2 * lane) = d;
      *(uint2*)(SHu + BBU2 + 2 * lane + 2 * (lane >> 2)) = d; }   // B words 2l,2l+1
    { uint2 d; d.x = o0;  d.y = o1;                      // c'=1: x[4l-1..4l+2]
      *(uint2*)(SHu + 176 + 2 * lane) = d; }
    { uint2 d; d.x = e1p; d.y = e0;                      // c'=2: x[4l-2..4l+1]
      *(uint2*)(SHu + 344 + 2 * lane) = d; }
    { uint2 d; d.x = o1p; d.y = o0;                      // c'=3: x[4l-3..4l]
      *(uint2*)(SHu + 512 + 2 * lane) = d; }
    {   // tail patches x253..x256: 7 u32 writes distributed over lanes 0-6
        unsigned int p256   = pack2h(s256f, 0.f);
        unsigned int p55_56 = pack2h(x255, s256f);
        unsigned int p54_55 = pack2h(x254, x255);
        unsigned int p53_54 = pack2h(x253, x254);
        if (lane < 7) {
            int adr = (lane == 0) ? 136 : (lane == 1) ? 304 :
                      (lane == 2) ? 472 : (lane == 3) ? 473 :
                      (lane == 4) ? 640 : (lane == 5) ? 641 : 822;
            unsigned int pvv =
                (lane == 0 || lane == 3 || lane == 6) ? p256 :
                (lane == 1 || lane == 5) ? p55_56 :
                (lane == 2) ? p54_55 : p53_54;
            SHu[adr] = pvv;
        }
    }

    // ---------------- phase 2: cumsum of squares (fp32, DPP scan) ----------------
    float p0 = q.x * q.x;
    float p1 = p0 + q.y * q.y;
    float p2 = p1 + q.z * q.z;
    float p3 = p2 + q.w * q.w;
    float sc = wave_iscan_add(p3);
    const float csbase = sc - p3;
    const float csx = csbase + p0, csy = csbase + p1, csz = csbase + p2, csw_ = csbase + p3;
    {
        float4 c4; c4.x = csx; c4.y = csy; c4.z = csz; c4.w = csw_;
        *(float4*)(SBf + CSB + 4 * lane) = c4;          // for reversed reads
    }
    float totE = __shfl(sc, 63) + s256f * s256f;
    if (lane == 63) SBf[CSB + 256] = totE;

    // ---------------- phase 3: autocorr via 9x mfma_f32_16x16x32_f16 -------------
    // A[m][k] = x_ext[k-m]; B[k][n] = x[k+16n]; D[m][n] = corr[16n+m].
    // Frags read as 2 x uint2 (b64) - bank-conflict-free by the P/pad design;
    // runtime addr mod 4 in {0,2} prevents b128 re-merge.
    const int m  = lane & 15;
    const int kb = lane >> 4;
    const int cA = m & 3, tq = m >> 2;
    const int auv = 8 + 168 * cA - 2 * tq + 4 * kb;
    const int w0 = 8 * m + 4 * kb;
    const int bbv = BBU2 + w0 + 2 * (w0 >> 3);           // per KK: +20

    f32x4 acc = {0.f, 0.f, 0.f, 0.f};
#define MSTEP(KK)                                                                \
    {                                                                            \
        uint2 alo = *(const uint2*)(SHu + auv + 16 * (KK));                      \
        uint2 ahi = *(const uint2*)(SHu + auv + 16 * (KK) + 2);                  \
        uint2 blo = *(const uint2*)(SHu + bbv + 20 * (KK));                      \
        uint2 bhi = *(const uint2*)(SHu + bbv + 20 * (KK) + 2);                  \
        U4H8 ua, ub;                                                             \
        ua.u.x = alo.x; ua.u.y = alo.y; ua.u.z = ahi.x; ua.u.w = ahi.y;          \
        ub.u.x = blo.x; ub.u.y = blo.y; ub.u.z = bhi.x; ub.u.w = bhi.y;          \
        acc = __builtin_amdgcn_mfma_f32_16x16x32_f16(ua.h, ub.h, acc, 0, 0, 0);  \
    }
    MSTEP(0) MSTEP(1) MSTEP(2) MSTEP(3) MSTEP(4)
    MSTEP(5) MSTEP(6) MSTEP(7) MSTEP(8)
#undef MSTEP

    // ---------------- phase 4: transpose D -> lane j owns corr[4j..4j+3] ---------
    {
        const int jj = 4 * m + kb;
        float4 av; av.x = acc[0]; av.y = acc[1]; av.z = acc[2]; av.w = acc[3];
        *(float4*)(SBf + DTB + 4 * jj + 4 * (jj >> 3)) = av;
    }
    float a0, a1, a2, a3;
    {
        const int rb = 4 * lane + 4 * (lane >> 3);
        float4 cr = *(const float4*)(SBf + DTB + rb);
        a0 = cr.x; a1 = cr.y; a2 = cr.z; a3 = cr.w;
    }

    // ---------------- phase 5: CMND (DPP scan, cd in regs) -----------------------
    float4 csr  = *(const float4*)(SBf + CSB + 252 - 4 * lane);
    float csTop = SBf[CSB + 256 - 4 * lane];

    float d0 = csTop - 2.0f * a0 + totE - csx;
    float d1 = csr.w - 2.0f * a1 + totE - csy;
    float d2 = csr.z - 2.0f * a2 + totE - csz;
    float d3 = csr.y - 2.0f * a3 + totE - csw_;
    if (lane == 0) d0 = 0.0f;                 // diff[0] excluded from prefix
    float l0 = d0, l1 = l0 + d1, l2 = l1 + d2, l3 = l2 + d3;
    float scn = wave_iscan_add(l3);
    float pb = scn - l3;
    const int gbase = 4 * lane;               // global tau idx of slot 0
    float cd0 = d0 * (float)(gbase + 0) * frcp(pb + l0 + 1e-7f);
    float cd1 = d1 * (float)(gbase + 1) * frcp(pb + l1 + 1e-7f);
    float cd2 = d2 * (float)(gbase + 2) * frcp(pb + l2 + 1e-7f);
    float cd3 = d3 * (float)(gbase + 3) * frcp(pb + l3 + 1e-7f);

    // ---------------- phase 6: threshold + tau fully in registers (R12-proven) ---
    const float prev3 = __shfl_up(cd3, 1);    // value at g-1 (junk at lane0: masked)
    const float next0 = __shfl_down(cd0, 1);  // value at g+4 (junk at lane63: masked)

    int thr = 0, lmm = 0;
    float sh0 = 0.f, sh1 = 0.f, sh2 = 0.f, sh3 = 0.f;
#define SLOT(S, PP, CC, NN, SH)                                                  \
    {                                                                            \
        const int i = gbase + (S) - TAU_MINC;                                    \
        const bool val = (i >= 0) && (i < C_LEN);                                \
        if (val && (CC) < 0.1f) thr |= (1 << (S));                               \
        const bool Lc = (i == 0) || ((CC) - (PP) <= 0.0f);                       \
        const bool Rc = (i == C_LEN - 1) || ((NN) - (CC) >= 0.0f);               \
        if (val && Lc && Rc) lmm |= (1 << (S));                                  \
        if (i >= 1 && i <= C_LEN - 2) {                                          \
            const float aa = (NN) + (PP) - 2.0f * (CC);                          \
            const float bb = 0.5f * ((NN) - (PP));                               \
            SH = (fabsf(bb) >= fabsf(aa)) ? 0.0f : (-bb * frcp(aa));             \
        }                                                                        \
    }
    SLOT(0, prev3, cd0, cd1, sh0)
    SLOT(1, cd0,   cd1, cd2, sh1)
    SLOT(2, cd1,   cd2, cd3, sh2)
    SLOT(3, cd2,   cd3, next0, sh3)
#undef SLOT

    unsigned long long bt = __ballot(thr != 0);
    int thold = C_LEN;
    if (bt != 0ULL) {
        const int Lw = __ffsll(bt) - 1;
        const int bits = __builtin_amdgcn_readlane(thr, Lw);
        const int ifirst = 4 * Lw + (__ffs(bits) - 1) - TAU_MINC;
        thold = (ifirst == 0) ? C_LEN : ifirst;
    }

    int lm2 = lmm;
    const int gmin = thold + TAU_MINC;
    if (gbase + 3 < gmin) lm2 = 0;
    else if (gbase < gmin) lm2 &= ~((1 << (gmin - gbase)) - 1);
    unsigned long long bl = __ballot(lm2 != 0);
    int tau = 0;
    if (bl != 0ULL) {
        const int Lw2 = __ffsll(bl) - 1;
        const int bits2 = __builtin_amdgcn_readlane(lm2, Lw2);
        tau = 4 * Lw2 + (__ffs(bits2) - 1) - TAU_MINC;
    }

    // ---------------- phase 7: parabolic interp + pitch --------------------------
    float pv = 0.0f;
    if (tau > 0) {                             // wave-uniform
        const int gt = tau + TAU_MINC;
        const int ln = gt >> 2, sl = gt & 3;
        float shsel = (sl == 0) ? sh0 : (sl == 1) ? sh1 : (sl == 2) ? sh2 : sh3;
        const float shift = __shfl(shsel, ln);
        pv = 16000.0f / ((float)(gt + 1) + shift);
    }
    if (lane == 0) pitch[frame] = pv;

    }   // persistent frame loop
}

// 30-wide median (index 14 of ascending sort), edge-padded (15,14).
// Bitonic sort network on 32 (2x +INF pads): 240 CE vs 900 counting-pass.
__global__ __launch_bounds__(256) void median_k(const float* __restrict__ pitch,
                                                float* __restrict__ out) {
    int idx = blockIdx.x * blockDim.x + threadIdx.x;
    if (idx >= NFRAMES) return;
    int b = idx / NF;
    int f = idx - b * NF;
    const float* p = pitch + b * NF;
    float v[32];
#pragma unroll
    for (int k = 0; k < 30; ++k) {
        int j = f + k - 15;
        j = (j < 0) ? 0 : ((j > NF - 1) ? NF - 1 : j);
        v[k] = p[j];
    }
    v[30] = 3.0e38f; v[31] = 3.0e38f;
#pragma unroll
    for (int k = 2; k <= 32; k <<= 1) {
#pragma unroll
        for (int j = k >> 1; j > 0; j >>= 1) {
#pragma unroll
            for (int i = 0; i < 32; ++i) {
                int l = i ^ j;
                if (l > i) {
                    bool up = ((i & k) == 0);
                    float a = v[i], c = v[l];
                    float mn = fminf(a, c), mx = fmaxf(a, c);
                    v[i] = up ? mn : mx;
                    v[l] = up ? mx : mn;
                }
            }
        }
    }
    out[idx] = v[14];
}

extern "C" void kernel_launch(void* const* d_in, const int* in_sizes, int n_in,
                              void* d_out, int out_size, void* d_ws, size_t ws_size,
                              hipStream_t stream) {
    (void)in_sizes; (void)n_in; (void)out_size; (void)ws_size;
    const float* in = (const float*)d_in[0];
    float* out = (float*)d_out;
    float* pitch = (float*)d_ws;     // NFRAMES floats = 256 KB scratch

    yin_frames<<<GRIDB, 128, 0, stream>>>(in, pitch);
    median_k<<<(NFRAMES + 255) / 256, 256, 0, stream>>>(pitch, out);
}

// Round 16
// 46.205 us; speedup vs baseline: 2.4726x; 1.1286x over previous
//
#include <hip/hip_runtime.h>
#include <math.h>

// YIN pitch, MI355X. Constants from reference:
//   SR=16000, STRIDES=160, W=257, TAU_MAX=213, TAU_MIN=26, C=187, MEDIAN=30
#define T_LEN    160000
#define STRIDES  160
#define NF       1001
#define NB       64
#define TAU_MINC 26
#define C_LEN    187
#define NFRAMES  (NB * NF)     // 64064
#define GRIDB    4096          // 16 blocks/CU x 256 CU = 32 waves/CU (HW cap)

// ---- Per-wave LDS map (u32 units) -------------------------------------------
// A: 4 shifted copies for b64 alignment classes mod 4 (R13-proven). Copy c'
//   base P(c') = 8 + 168*c'; x_ext[j] at half S+j, S = 2*P + c'. Conflict-free.
//   A spans u32 [0, 656).
// B: base BBU2 == 2 mod 4; word w at BBU2 + w + 2*(w>>3); spans [662, 990).
//   Words 129..263 are the ZERO-ONCE tail (x[257..527] = 0) - nothing may
//   alias them (R14 bug: DT at 824 overwrote this tail -> absmax 576).
// DT: floats [992, 1276) - ABOVE B's extent, dedicated.
#define WAVE_U32 1276
#define BBU2     662
#define DTB      992

typedef __fp16 half2_t __attribute__((ext_vector_type(2)));
typedef __fp16 f16x8   __attribute__((ext_vector_type(8)));
typedef float  f32x4   __attribute__((ext_vector_type(4)));
union H2U  { half2_t h; unsigned int u; };
union U4H8 { uint4 u; f16x8 h; };

__device__ __forceinline__ unsigned int pack2h(float a, float b) {
    H2U x;
#if __has_builtin(__builtin_amdgcn_cvt_pkrtz)
    x.h = __builtin_amdgcn_cvt_pkrtz(a, b);
#else
    x.h.x = (__fp16)a; x.h.y = (__fp16)b;
#endif
    return x.u;
}
__device__ __forceinline__ float frcp(float x) {
#if __has_builtin(__builtin_amdgcn_rcpf)
    return __builtin_amdgcn_rcpf(x);
#else
    return 1.0f / x;
#endif
}

// ---- DPP wave-inclusive scan (VALU pipe, no LDS) - R10/R12-proven ------------
template<int CTRL, int RMASK, bool BC>
__device__ __forceinline__ float dpp_add(float v) {
    union { float f; int i; } a, r;
    a.f = v;
    r.i = __builtin_amdgcn_update_dpp(0, a.i, CTRL, RMASK, 0xF, BC);
    return v + r.f;
}
__device__ __forceinline__ float wave_iscan_add(float x) {
    float v = x;
    v = dpp_add<0x111, 0xF, true>(v);    // row_shr:1
    v = dpp_add<0x112, 0xF, true>(v);    // row_shr:2
    v = dpp_add<0x114, 0xF, true>(v);    // row_shr:4
    v = dpp_add<0x118, 0xF, true>(v);    // row_shr:8
    v = dpp_add<0x142, 0xA, false>(v);   // row_bcast:15 -> rows 1,3
    v = dpp_add<0x143, 0xC, false>(v);   // row_bcast:31 -> rows 2,3
    return v;
}

// guarded frame load (float4 window chunk + sample 256)
#define LOADQ(FR, Q, S2)                                                         \
    {                                                                            \
        const int bb = (FR) / NF;                                                \
        const int ff = (FR) - bb * NF;                                           \
        const float* sp = in + (size_t)bb * T_LEN;                               \
        const int st = ff * STRIDES;                                             \
        int ei = st + 4 * lane;                                                  \
        if (ei + 3 < T_LEN) {                                                    \
            Q = *(const float4*)(sp + ei);                                       \
        } else {                                                                 \
            Q.x = (ei + 0 < T_LEN) ? sp[ei + 0] : 0.f;                           \
            Q.y = (ei + 1 < T_LEN) ? sp[ei + 1] : 0.f;                           \
            Q.z = (ei + 2 < T_LEN) ? sp[ei + 2] : 0.f;                           \
            Q.w = (ei + 3 < T_LEN) ? sp[ei + 3] : 0.f;                           \
        }                                                                        \
        S2 = 0.0f;                                                               \
        if (lane == 0) { int e2 = st + 256; S2 = (e2 < T_LEN) ? sp[e2] : 0.f; }  \
    }

// R2-R4 lesson: arrays with computed indices survive SROA as allocas ->
// scratch -> 6 GB HBM. Named scalars / const-indexed vectors only.

__global__ __launch_bounds__(128, 8) void yin_frames(const float* __restrict__ in,
                                                     float* __restrict__ pitch) {
    __shared__ __align__(16) unsigned int SB_[2][WAVE_U32];

    const int wid  = threadIdx.x >> 6;
    const int lane = threadIdx.x & 63;
    unsigned int* SHu = SB_[wid];
    float* SBf = (float*)SHu;

    // ---------------- zero-once: A+B region [0,1024) (DT is above 992... ----------
    // [992,1024) overlaps DT but DT is write-before-read every frame - harmless)
    {
        uint4 z; z.x = 0u; z.y = 0u; z.z = 0u; z.w = 0u;
#pragma unroll
        for (int k = 0; k < 4; ++k) *(uint4*)(SHu + 4 * lane + 256 * k) = z;
    }

    const int fstride = GRIDB * 2;
    int frame = blockIdx.x * 2 + wid;
    float4 q; float s256p;
    LOADQ(frame, q, s256p)                       // first frame (always < NFRAMES)

    for (; frame < NFRAMES; frame += fstride) {

    // ---------------- prefetch NEXT frame's data (hides HBM/L2 latency) ----------
    float4 qn; qn.x = 0.f; qn.y = 0.f; qn.z = 0.f; qn.w = 0.f;
    float s256n = 0.0f;
    const int fnext = frame + fstride;
    if (fnext < NFRAMES) LOADQ(fnext, qn, s256n)

    const float s256f = __shfl(s256p, 0);

    // ---------------- phase 1: build packed variants + stage -----------------------
    unsigned int e0 = pack2h(q.x, q.y), e1 = pack2h(q.z, q.w);
    float prevw = __shfl_up(q.w, 1); if (lane == 0) prevw = 0.f;
    unsigned int o0 = pack2h(prevw, q.x), o1 = pack2h(q.y, q.z);
    unsigned int e1p = __shfl_up(e1, 1); if (lane == 0) e1p = 0u;  // x[4l-2],x[4l-1]
    unsigned int o1p = __shfl_up(o1, 1); if (lane == 0) o1p = 0u;  // x[4l-3],x[4l-2]
    const float x253 = __shfl(q.y, 63);
    const float x254 = __shfl(q.z, 63);
    const float x255 = __shfl(q.w, 63);

    // A copies (4, shifted; bases 8,176,344,512) + B (padded w+2*(w>>3)). R13-proven.
    { uint2 d; d.x = e0;  d.y = e1;                      // c'=0: x[4l..4l+3]
      *(uint2*)(SHu + 8   + 2 * lane) = d;
      *(uint2*)(SHu + BBU2 + 2 * lane + 2 * (lane >> 2)) = d; }   // B words 2l,2l+1
    { uint2 d; d.x = o0;  d.y = o1;                      // c'=1: x[4l-1..4l+2]
      *(uint2*)(SHu + 176 + 2 * lane) = d; }
    { uint2 d; d.x = e1p; d.y = e0;                      // c'=2: x[4l-2..4l+1]
      *(uint2*)(SHu + 344 + 2 * lane) = d; }
    { uint2 d; d.x = o1p; d.y = o0;                      // c'=3: x[4l-3..4l]
      *(uint2*)(SHu + 512 + 2 * lane) = d; }
    {   // tail patches x253..x256: 7 u32 writes distributed over lanes 0-6
        unsigned int p256   = pack2h(s256f, 0.f);
        unsigned int p55_56 = pack2h(x255, s256f);
        unsigned int p54_55 = pack2h(x254, x255);
        unsigned int p53_54 = pack2h(x253, x254);
        if (lane < 7) {
            int adr = (lane == 0) ? 136 : (lane == 1) ? 304 :
                      (lane == 2) ? 472 : (lane == 3) ? 473 :
                      (lane == 4) ? 640 : (lane == 5) ? 641 : 822;
            unsigned int pvv =
                (lane == 0 || lane == 3 || lane == 6) ? p256 :
                (lane == 1 || lane == 5) ? p55_56 :
                (lane == 2) ? p54_55 : p53_54;
            SHu[adr] = pvv;
        }
    }

    // ---------------- phase 2: cumsum of squares (fp32, DPP scan) ----------------
    float p0 = q.x * q.x;
    float p1 = p0 + q.y * q.y;
    float p2 = p1 + q.z * q.z;
    float p3 = p2 + q.w * q.w;
    float sc = wave_iscan_add(p3);
    const float csbase = sc - p3;
    const float csx = csbase + p0, csy = csbase + p1, csz = csbase + p2, csw_ = csbase + p3;
    float totE = __shfl(sc, 63) + s256f * s256f;

    // ---------------- phase 3: autocorr via 9x mfma_f32_16x16x32_f16 -------------
    // A[m][k] = x_ext[k-m]; B[k][n] = x[k+16n]; D[m][n] = corr[16n+m]. R13-proven.
    const int m  = lane & 15;
    const int kb = lane >> 4;
    const int cA = m & 3, tq = m >> 2;
    const int auv = 8 + 168 * cA - 2 * tq + 4 * kb;
    const int w0 = 8 * m + 4 * kb;
    const int bbv = BBU2 + w0 + 2 * (w0 >> 3);           // per KK: +20

    f32x4 acc = {0.f, 0.f, 0.f, 0.f};
#define MSTEP(KK)                                                                \
    {                                                                            \
        uint2 alo = *(const uint2*)(SHu + auv + 16 * (KK));                      \
        uint2 ahi = *(const uint2*)(SHu + auv + 16 * (KK) + 2);                  \
        uint2 blo = *(const uint2*)(SHu + bbv + 20 * (KK));                      \
        uint2 bhi = *(const uint2*)(SHu + bbv + 20 * (KK) + 2);                  \
        U4H8 ua, ub;                                                             \
        ua.u.x = alo.x; ua.u.y = alo.y; ua.u.z = ahi.x; ua.u.w = ahi.y;          \
        ub.u.x = blo.x; ub.u.y = blo.y; ub.u.z = bhi.x; ub.u.w = bhi.y;          \
        acc = __builtin_amdgcn_mfma_f32_16x16x32_f16(ua.h, ub.h, acc, 0, 0, 0);  \
    }
    MSTEP(0) MSTEP(1) MSTEP(2) MSTEP(3) MSTEP(4)
    MSTEP(5) MSTEP(6) MSTEP(7) MSTEP(8)
#undef MSTEP

    // ---------------- phase 4: transpose D -> lane j owns corr[4j..4j+3] ---------
    {
        const int jj = 4 * m + kb;
        float4 av; av.x = acc[0]; av.y = acc[1]; av.z = acc[2]; av.w = acc[3];
        *(float4*)(SBf + DTB + 4 * jj + 4 * (jj >> 3)) = av;
    }
    float a0, a1, a2, a3;
    {
        const int rb = 4 * lane + 4 * (lane >> 3);
        float4 cr = *(const float4*)(SBf + DTB + rb);
        a0 = cr.x; a1 = cr.y; a2 = cr.z; a3 = cr.w;
    }

    // ---------------- phase 5: CMND (reversed cs via XOR shuffles, no LDS) -------
    // cs[255-4l],cs[254-4l],cs[253-4l] live in lane 63-l (= 63^l); cs[256-4l]
    // is csx of lane (64-l)&63 (junk at l=0; d0 forced 0 there anyway).
    const int lrev = 63 ^ lane;
    const float csRw = __shfl(csw_, lrev);    // cs[255-4l]
    const float csRz = __shfl(csz,  lrev);    // cs[254-4l]
    const float csRy = __shfl(csy,  lrev);    // cs[253-4l]
    const float csTop = __shfl(csx, (64 - lane) & 63);   // cs[256-4l], junk @ l=0

    float d0 = csTop - 2.0f * a0 + totE - csx;
    float d1 = csRw - 2.0f * a1 + totE - csy;
    float d2 = csRz - 2.0f * a2 + totE - csz;
    float d3 = csRy - 2.0f * a3 + totE - csw_;
    if (lane == 0) d0 = 0.0f;                 // diff[0] excluded from prefix
    float l0 = d0, l1 = l0 + d1, l2 = l1 + d2, l3 = l2 + d3;
    float scn = wave_iscan_add(l3);
    float pb = scn - l3;
    const int gbase = 4 * lane;               // global tau idx of slot 0
    float cd0 = d0 * (float)(gbase + 0) * frcp(pb + l0 + 1e-7f);
    float cd1 = d1 * (float)(gbase + 1) * frcp(pb + l1 + 1e-7f);
    float cd2 = d2 * (float)(gbase + 2) * frcp(pb + l2 + 1e-7f);
    float cd3 = d3 * (float)(gbase + 3) * frcp(pb + l3 + 1e-7f);

    // ---------------- phase 6: threshold + tau fully in registers (R12-proven) ---
    const float prev3 = __shfl_up(cd3, 1);    // value at g-1 (junk at lane0: masked)
    const float next0 = __shfl_down(cd0, 1);  // value at g+4 (junk at lane63: masked)

    int thr = 0, lmm = 0;
    float sh0 = 0.f, sh1 = 0.f, sh2 = 0.f, sh3 = 0.f;
#define SLOT(S, PP, CC, NN, SH)                                                  \
    {                                                                            \
        const int i = gbase + (S) - TAU_MINC;                                    \
        const bool val = (i >= 0) && (i < C_LEN);                                \
        if (val && (CC) < 0.1f) thr |= (1 << (S));                               \
        const bool Lc = (i == 0) || ((CC) - (PP) <= 0.0f);                       \
        const bool Rc = (i == C_LEN - 1) || ((NN) - (CC) >= 0.0f);               \
        if (val && Lc && Rc) lmm |= (1 << (S));                                  \
        if (i >= 1 && i <= C_LEN - 2) {                                          \
            const float aa = (NN) + (PP) - 2.0f * (CC);                          \
            const float bb = 0.5f * ((NN) - (PP));                               \
            SH = (fabsf(bb) >= fabsf(aa)) ? 0.0f : (-bb * frcp(aa));             \
        }                                                                        \
    }
    SLOT(0, prev3, cd0, cd1, sh0)
    SLOT(1, cd0,   cd1, cd2, sh1)
    SLOT(2, cd1,   cd2, cd3, sh2)
    SLOT(3, cd2,   cd3, next0, sh3)
#undef SLOT

    unsigned long long bt = __ballot(thr != 0);
    int thold = C_LEN;
    if (bt != 0ULL) {
        const int Lw = __ffsll(bt) - 1;
        const int bits = __builtin_amdgcn_readlane(thr, Lw);
        const int ifirst = 4 * Lw + (__ffs(bits) - 1) - TAU_MINC;
        thold = (ifirst == 0) ? C_LEN : ifirst;
    }

    int lm2 = lmm;
    const int gmin = thold + TAU_MINC;
    if (gbase + 3 < gmin) lm2 = 0;
    else if (gbase < gmin) lm2 &= ~((1 << (gmin - gbase)) - 1);
    unsigned long long bl = __ballot(lm2 != 0);
    int tau = 0;
    if (bl != 0ULL) {
        const int Lw2 = __ffsll(bl) - 1;
        const int bits2 = __builtin_amdgcn_readlane(lm2, Lw2);
        tau = 4 * Lw2 + (__ffs(bits2) - 1) - TAU_MINC;
    }

    // ---------------- phase 7: parabolic interp + pitch --------------------------
    float pv = 0.0f;
    if (tau > 0) {                             // wave-uniform
        const int gt = tau + TAU_MINC;
        const int ln = gt >> 2, sl = gt & 3;
        float shsel = (sl == 0) ? sh0 : (sl == 1) ? sh1 : (sl == 2) ? sh2 : sh3;
        const float shift = __shfl(shsel, ln);
        pv = 16000.0f / ((float)(gt + 1) + shift);
    }
    if (lane == 0) pitch[frame] = pv;

    q = qn; s256p = s256n;                     // rotate prefetched frame in
    }   // persistent frame loop
}

// 30-wide median (index 14 of ascending sort), edge-padded (15,14).
// Bitonic sort network on 32 (2x +INF pads).
__global__ __launch_bounds__(256) void median_k(const float* __restrict__ pitch,
                                                float* __restrict__ out) {
    int idx = blockIdx.x * blockDim.x + threadIdx.x;
    if (idx >= NFRAMES) return;
    int b = idx / NF;
    int f = idx - b * NF;
    const float* p = pitch + b * NF;
    float v[32];
#pragma unroll
    for (int k = 0; k < 30; ++k) {
        int j = f + k - 15;
        j = (j < 0) ? 0 : ((j > NF - 1) ? NF - 1 : j);
        v[k] = p[j];
    }
    v[30] = 3.0e38f; v[31] = 3.0e38f;
#pragma unroll
    for (int k = 2; k <= 32; k <<= 1) {
#pragma unroll
        for (int j = k >> 1; j > 0; j >>= 1) {
#pragma unroll
            for (int i = 0; i < 32; ++i) {
                int l = i ^ j;
                if (l > i) {
                    bool up = ((i & k) == 0);
                    float a = v[i], c = v[l];
                    float mn = fminf(a, c), mx = fmaxf(a, c);
                    v[i] = up ? mn : mx;
                    v[l] = up ? mx : mn;
                }
            }
        }
    }
    out[idx] = v[14];
}

extern "C" void kernel_launch(void* const* d_in, const int* in_sizes, int n_in,
                              void* d_out, int out_size, void* d_ws, size_t ws_size,
                              hipStream_t stream) {
    (void)in_sizes; (void)n_in; (void)out_size; (void)ws_size;
    const float* in = (const float*)d_in[0];
    float* out = (float*)d_out;
    float* pitch = (float*)d_ws;     // NFRAMES floats = 256 KB scratch

    yin_frames<<<GRIDB, 128, 0, stream>>>(in, pitch);
    median_k<<<(NFRAMES + 255) / 256, 256, 0, stream>>>(pitch, out);
}

// Round 17
// 40.203 us; speedup vs baseline: 2.8418x; 1.1493x over previous
//
#include <hip/hip_runtime.h>
#include <math.h>

// YIN pitch, MI355X. Constants from reference:
//   SR=16000, STRIDES=160, W=257, TAU_MAX=213, TAU_MIN=26, C=187, MEDIAN=30
#define T_LEN    160000
#define STRIDES  160
#define NF       1001
#define NB       64
#define TAU_MINC 26
#define C_LEN    187
#define NFRAMES  (NB * NF)     // 64064
#define GRIDB    4096          // 16 blocks/CU x 256 CU = 32 waves/CU (HW cap)

// ---- Per-wave LDS map (u32 units) -------------------------------------------
// A: 4 shifted copies for b64 alignment classes mod 4 (R13-proven). Copy c'
//   base P(c') = 8 + 168*c'; x_ext[j] at half S+j, S = 2*P + c'. Conflict-free.
//   A spans u32 [0, 656).
// B: base BBU2 == 2 mod 4; word w at BBU2 + w + 2*(w>>3); spans [662, 990).
//   Words 129..263 are the ZERO-ONCE tail (x[257..527] = 0) - nothing may
//   alias them (R14 bug: DT at 824 overwrote this tail -> absmax 576).
// DT: floats [992, 1276) - ABOVE B's extent, dedicated.
#define WAVE_U32 1276
#define BBU2     662
#define DTB      992

typedef __fp16 half2_t __attribute__((ext_vector_type(2)));
typedef __fp16 f16x8   __attribute__((ext_vector_type(8)));
typedef float  f32x4   __attribute__((ext_vector_type(4)));
union H2U  { half2_t h; unsigned int u; };
union U4H8 { uint4 u; f16x8 h; };

__device__ __forceinline__ unsigned int pack2h(float a, float b) {
    H2U x;
#if __has_builtin(__builtin_amdgcn_cvt_pkrtz)
    x.h = __builtin_amdgcn_cvt_pkrtz(a, b);
#else
    x.h.x = (__fp16)a; x.h.y = (__fp16)b;
#endif
    return x.u;
}
__device__ __forceinline__ float frcp(float x) {
#if __has_builtin(__builtin_amdgcn_rcpf)
    return __builtin_amdgcn_rcpf(x);
#else
    return 1.0f / x;
#endif
}

// ---- DPP helpers (VALU pipe - keeps work OFF the LDS pipe) -------------------
// wave_shr:1 = 0x138, wave_shl:1 = 0x130. bound_ctrl=true -> OOB lanes get 0.
template<int CTRL>
__device__ __forceinline__ float dpp_movf(float v) {
    union { float f; int i; } a, r;
    a.f = v;
    r.i = __builtin_amdgcn_update_dpp(0, a.i, CTRL, 0xF, 0xF, true);
    return r.f;
}
template<int CTRL>
__device__ __forceinline__ unsigned int dpp_movu(unsigned int v) {
    return (unsigned int)__builtin_amdgcn_update_dpp(0, (int)v, CTRL, 0xF, 0xF, true);
}
__device__ __forceinline__ float readlanef(float v, int l) {
    union { float f; int i; } a, r;
    a.f = v;
    r.i = __builtin_amdgcn_readlane(a.i, l);
    return r.f;
}

// ---- DPP wave-inclusive scan (VALU pipe, no LDS) - R10/R12-proven ------------
template<int CTRL, int RMASK, bool BC>
__device__ __forceinline__ float dpp_add(float v) {
    union { float f; int i; } a, r;
    a.f = v;
    r.i = __builtin_amdgcn_update_dpp(0, a.i, CTRL, RMASK, 0xF, BC);
    return v + r.f;
}
__device__ __forceinline__ float wave_iscan_add(float x) {
    float v = x;
    v = dpp_add<0x111, 0xF, true>(v);    // row_shr:1
    v = dpp_add<0x112, 0xF, true>(v);    // row_shr:2
    v = dpp_add<0x114, 0xF, true>(v);    // row_shr:4
    v = dpp_add<0x118, 0xF, true>(v);    // row_shr:8
    v = dpp_add<0x142, 0xA, false>(v);   // row_bcast:15 -> rows 1,3
    v = dpp_add<0x143, 0xC, false>(v);   // row_bcast:31 -> rows 2,3
    return v;
}

// guarded frame load (float4 window chunk + sample 256, broadcast on all lanes)
#define LOADQ(FR, Q, S2)                                                         \
    {                                                                            \
        const int bb = (FR) / NF;                                                \
        const int ff = (FR) - bb * NF;                                           \
        const float* sp = in + (size_t)bb * T_LEN;                               \
        const int st = ff * STRIDES;                                             \
        int ei = st + 4 * lane;                                                  \
        if (ei + 3 < T_LEN) {                                                    \
            Q = *(const float4*)(sp + ei);                                       \
        } else {                                                                 \
            Q.x = (ei + 0 < T_LEN) ? sp[ei + 0] : 0.f;                           \
            Q.y = (ei + 1 < T_LEN) ? sp[ei + 1] : 0.f;                           \
            Q.z = (ei + 2 < T_LEN) ? sp[ei + 2] : 0.f;                           \
            Q.w = (ei + 3 < T_LEN) ? sp[ei + 3] : 0.f;                           \
        }                                                                        \
        const int e2 = st + 256;                                                 \
        S2 = (e2 < T_LEN) ? sp[e2] : 0.f;   /* same addr all lanes: 1 txn */     \
    }

// R2-R4 lesson: arrays with computed indices survive SROA as allocas ->
// scratch -> 6 GB HBM. Named scalars / const-indexed vectors only.

__global__ __launch_bounds__(128, 8) void yin_frames(const float* __restrict__ in,
                                                     float* __restrict__ pitch) {
    __shared__ __align__(16) unsigned int SB_[2][WAVE_U32];

    const int wid  = threadIdx.x >> 6;
    const int lane = threadIdx.x & 63;
    unsigned int* SHu = SB_[wid];
    float* SBf = (float*)SHu;

    // ---------------- zero-once: A+B region [0,1024) ------------------------------
    // ([992,1024) overlaps DT but DT is write-before-read every frame - harmless)
    {
        uint4 z; z.x = 0u; z.y = 0u; z.z = 0u; z.w = 0u;
#pragma unroll
        for (int k = 0; k < 4; ++k) *(uint4*)(SHu + 4 * lane + 256 * k) = z;
    }

    const int fstride = GRIDB * 2;
    int frame = blockIdx.x * 2 + wid;
    float4 q; float s256f;
    LOADQ(frame, q, s256f)                       // first frame (always < NFRAMES)

    for (; frame < NFRAMES; frame += fstride) {

    // ---------------- prefetch NEXT frame's data (hides HBM/L2 latency) ----------
    float4 qn; qn.x = 0.f; qn.y = 0.f; qn.z = 0.f; qn.w = 0.f;
    float s256n = 0.0f;
    const int fnext = frame + fstride;
    if (fnext < NFRAMES) LOADQ(fnext, qn, s256n)

    // ---------------- phase 1: build packed variants + stage ---------------------
    // Lane-shift shuffles done on the VALU pipe (DPP wave_shr:1, lane0 -> 0);
    // broadcasts via v_readlane. No ds_bpermute here (LDS pipe is the wall).
    unsigned int e0 = pack2h(q.x, q.y), e1 = pack2h(q.z, q.w);
    const float prevw = dpp_movf<0x138>(q.w);            // x[4l-1], lane0 -> 0
    unsigned int o0 = pack2h(prevw, q.x), o1 = pack2h(q.y, q.z);
    unsigned int e1p = dpp_movu<0x138>(e1);              // x[4l-2],x[4l-1]
    unsigned int o1p = dpp_movu<0x138>(o1);              // x[4l-3],x[4l-2]
    const float x253 = readlanef(q.y, 63);
    const float x254 = readlanef(q.z, 63);
    const float x255 = readlanef(q.w, 63);

    // A copies (4, shifted; bases 8,176,344,512) + B (padded w+2*(w>>3)). R13-proven.
    { uint2 d; d.x = e0;  d.y = e1;                      // c'=0: x[4l..4l+3]
      *(uint2*)(SHu + 8   + 2 * lane) = d;
      *(uint2*)(SHu + BBU2 + 2 * lane + 2 * (lane >> 2)) = d; }   // B words 2l,2l+1
    { uint2 d; d.x = o0;  d.y = o1;                      // c'=1: x[4l-1..4l+2]
      *(uint2*)(SHu + 176 + 2 * lane) = d; }
    { uint2 d; d.x = e1p; d.y = e0;                      // c'=2: x[4l-2..4l+1]
      *(uint2*)(SHu + 344 + 2 * lane) = d; }
    { uint2 d; d.x = o1p; d.y = o0;                      // c'=3: x[4l-3..4l]
      *(uint2*)(SHu + 512 + 2 * lane) = d; }
    {   // tail patches x253..x256: 7 u32 writes distributed over lanes 0-6
        unsigned int p256   = pack2h(s256f, 0.f);
        unsigned int p55_56 = pack2h(x255, s256f);
        unsigned int p54_55 = pack2h(x254, x255);
        unsigned int p53_54 = pack2h(x253, x254);
        if (lane < 7) {
            int adr = (lane == 0) ? 136 : (lane == 1) ? 304 :
                      (lane == 2) ? 472 : (lane == 3) ? 473 :
                      (lane == 4) ? 640 : (lane == 5) ? 641 : 822;
            unsigned int pvv =
                (lane == 0 || lane == 3 || lane == 6) ? p256 :
                (lane == 1 || lane == 5) ? p55_56 :
                (lane == 2) ? p54_55 : p53_54;
            SHu[adr] = pvv;
        }
    }

    // ---------------- phase 2: cumsum of squares (fp32, DPP scan) ----------------
    float p0 = q.x * q.x;
    float p1 = p0 + q.y * q.y;
    float p2 = p1 + q.z * q.z;
    float p3 = p2 + q.w * q.w;
    float sc = wave_iscan_add(p3);
    const float csbase = sc - p3;
    const float csx = csbase + p0, csy = csbase + p1, csz = csbase + p2, csw_ = csbase + p3;
    float totE = readlanef(sc, 63) + s256f * s256f;

    // ---------------- phase 3: autocorr via 9x mfma_f32_16x16x32_f16 -------------
    // A[m][k] = x_ext[k-m]; B[k][n] = x[k+16n]; D[m][n] = corr[16n+m]. R13-proven.
    const int m  = lane & 15;
    const int kb = lane >> 4;
    const int cA = m & 3, tq = m >> 2;
    const int auv = 8 + 168 * cA - 2 * tq + 4 * kb;
    const int w0 = 8 * m + 4 * kb;
    const int bbv = BBU2 + w0 + 2 * (w0 >> 3);           // per KK: +20

    f32x4 acc = {0.f, 0.f, 0.f, 0.f};
#define MSTEP(KK)                                                                \
    {                                                                            \
        uint2 alo = *(const uint2*)(SHu + auv + 16 * (KK));                      \
        uint2 ahi = *(const uint2*)(SHu + auv + 16 * (KK) + 2);                  \
        uint2 blo = *(const uint2*)(SHu + bbv + 20 * (KK));                      \
        uint2 bhi = *(const uint2*)(SHu + bbv + 20 * (KK) + 2);                  \
        U4H8 ua, ub;                                                             \
        ua.u.x = alo.x; ua.u.y = alo.y; ua.u.z = ahi.x; ua.u.w = ahi.y;          \
        ub.u.x = blo.x; ub.u.y = blo.y; ub.u.z = bhi.x; ub.u.w = bhi.y;          \
        acc = __builtin_amdgcn_mfma_f32_16x16x32_f16(ua.h, ub.h, acc, 0, 0, 0);  \
    }
    MSTEP(0) MSTEP(1) MSTEP(2) MSTEP(3) MSTEP(4)
    MSTEP(5) MSTEP(6) MSTEP(7) MSTEP(8)
#undef MSTEP

    // ---------------- phase 4: transpose D -> lane j owns corr[4j..4j+3] ---------
    {
        const int jj = 4 * m + kb;
        float4 av; av.x = acc[0]; av.y = acc[1]; av.z = acc[2]; av.w = acc[3];
        *(float4*)(SBf + DTB + 4 * jj + 4 * (jj >> 3)) = av;
    }
    float a0, a1, a2, a3;
    {
        const int rb = 4 * lane + 4 * (lane >> 3);
        float4 cr = *(const float4*)(SBf + DTB + rb);
        a0 = cr.x; a1 = cr.y; a2 = cr.z; a3 = cr.w;
    }

    // ---------------- phase 5: CMND (reversed cs via XOR shuffles) ---------------
    // cs[255-4l],cs[254-4l],cs[253-4l] live in lane 63-l (= 63^l); cs[256-4l]
    // is csx of lane (64-l)&63 (junk at l=0; d0 forced 0 there anyway).
    const int lrev = 63 ^ lane;
    const float csRw = __shfl(csw_, lrev);    // cs[255-4l]
    const float csRz = __shfl(csz,  lrev);    // cs[254-4l]
    const float csRy = __shfl(csy,  lrev);    // cs[253-4l]
    const float csTop = __shfl(csx, (64 - lane) & 63);   // cs[256-4l], junk @ l=0

    float d0 = csTop - 2.0f * a0 + totE - csx;
    float d1 = csRw - 2.0f * a1 + totE - csy;
    float d2 = csRz - 2.0f * a2 + totE - csz;
    float d3 = csRy - 2.0f * a3 + totE - csw_;
    if (lane == 0) d0 = 0.0f;                 // diff[0] excluded from prefix
    float l0 = d0, l1 = l0 + d1, l2 = l1 + d2, l3 = l2 + d3;
    float scn = wave_iscan_add(l3);
    float pb = scn - l3;
    const int gbase = 4 * lane;               // global tau idx of slot 0
    float cd0 = d0 * (float)(gbase + 0) * frcp(pb + l0 + 1e-7f);
    float cd1 = d1 * (float)(gbase + 1) * frcp(pb + l1 + 1e-7f);
    float cd2 = d2 * (float)(gbase + 2) * frcp(pb + l2 + 1e-7f);
    float cd3 = d3 * (float)(gbase + 3) * frcp(pb + l3 + 1e-7f);

    // ---------------- phase 6: threshold + tau fully in registers ----------------
    // neighbor values via DPP (VALU), not bpermute. OOB lanes get 0: masked.
    const float prev3 = dpp_movf<0x138>(cd3); // value at g-1 (lane0: 0, masked)
    const float next0 = dpp_movf<0x130>(cd0); // value at g+4 (lane63: 0, masked)

    int thr = 0, lmm = 0;
    float sh0 = 0.f, sh1 = 0.f, sh2 = 0.f, sh3 = 0.f;
#define SLOT(S, PP, CC, NN, SH)                                                  \
    {                                                                            \
        const int i = gbase + (S) - TAU_MINC;                                    \
        const bool val = (i >= 0) && (i < C_LEN);                                \
        if (val && (CC) < 0.1f) thr |= (1 << (S));                               \
        const bool Lc = (i == 0) || ((CC) - (PP) <= 0.0f);                       \
        const bool Rc = (i == C_LEN - 1) || ((NN) - (CC) >= 0.0f);               \
        if (val && Lc && Rc) lmm |= (1 << (S));                                  \
        if (i >= 1 && i <= C_LEN - 2) {                                          \
            const float aa = (NN) + (PP) - 2.0f * (CC);                          \
            const float bb = 0.5f * ((NN) - (PP));                               \
            SH = (fabsf(bb) >= fabsf(aa)) ? 0.0f : (-bb * frcp(aa));             \
        }                                                                        \
    }
    SLOT(0, prev3, cd0, cd1, sh0)
    SLOT(1, cd0,   cd1, cd2, sh1)
    SLOT(2, cd1,   cd2, cd3, sh2)
    SLOT(3, cd2,   cd3, next0, sh3)
#undef SLOT

    unsigned long long bt = __ballot(thr != 0);
    int thold = C_LEN;
    if (bt != 0ULL) {
        const int Lw = __ffsll(bt) - 1;
        const int bits = __builtin_amdgcn_readlane(thr, Lw);
        const int ifirst = 4 * Lw + (__ffs(bits) - 1) - TAU_MINC;
        thold = (ifirst == 0) ? C_LEN : ifirst;
    }

    int lm2 = lmm;
    const int gmin = thold + TAU_MINC;
    if (gbase + 3 < gmin) lm2 = 0;
    else if (gbase < gmin) lm2 &= ~((1 << (gmin - gbase)) - 1);
    unsigned long long bl = __ballot(lm2 != 0);
    int tau = 0;
    if (bl != 0ULL) {
        const int Lw2 = __ffsll(bl) - 1;
        const int bits2 = __builtin_amdgcn_readlane(lm2, Lw2);
        tau = 4 * Lw2 + (__ffs(bits2) - 1) - TAU_MINC;
    }

    // ---------------- phase 7: parabolic interp + pitch --------------------------
    float pv = 0.0f;
    if (tau > 0) {                             // wave-uniform
        const int gt = tau + TAU_MINC;
        const int ln = gt >> 2, sl = gt & 3;
        float shsel = (sl == 0) ? sh0 : (sl == 1) ? sh1 : (sl == 2) ? sh2 : sh3;
        const float shift = readlanef(shsel, ln);   // SGPR-indexed readlane
        pv = 16000.0f / ((float)(gt + 1) + shift);
    }
    if (lane == 0) pitch[frame] = pv;

    q = qn; s256f = s256n;                     // rotate prefetched frame in
    }   // persistent frame loop
}

// 30-wide median (index 14 of ascending sort), edge-padded (15,14).
// Bitonic sort network on 32 (2x +INF pads).
__global__ __launch_bounds__(256) void median_k(const float* __restrict__ pitch,
                                                float* __restrict__ out) {
    int idx = blockIdx.x * blockDim.x + threadIdx.x;
    if (idx >= NFRAMES) return;
    int b = idx / NF;
    int f = idx - b * NF;
    const float* p = pitch + b * NF;
    float v[32];
#pragma unroll
    for (int k = 0; k < 30; ++k) {
        int j = f + k - 15;
        j = (j < 0) ? 0 : ((j > NF - 1) ? NF - 1 : j);
        v[k] = p[j];
    }
    v[30] = 3.0e38f; v[31] = 3.0e38f;
#pragma unroll
    for (int k = 2; k <= 32; k <<= 1) {
#pragma unroll
        for (int j = k >> 1; j > 0; j >>= 1) {
#pragma unroll
            for (int i = 0; i < 32; ++i) {
                int l = i ^ j;
                if (l > i) {
                    bool up = ((i & k) == 0);
                    float a = v[i], c = v[l];
                    float mn = fminf(a, c), mx = fmaxf(a, c);
                    v[i] = up ? mn : mx;
                    v[l] = up ? mx : mn;
                }
            }
        }
    }
    out[idx] = v[14];
}

extern "C" void kernel_launch(void* const* d_in, const int* in_sizes, int n_in,
                              void* d_out, int out_size, void* d_ws, size_t ws_size,
                              hipStream_t stream) {
    (void)in_sizes; (void)n_in; (void)out_size; (void)ws_size;
    const float* in = (const float*)d_in[0];
    float* out = (float*)d_out;
    float* pitch = (float*)d_ws;     // NFRAMES floats = 256 KB scratch

    yin_frames<<<GRIDB, 128, 0, stream>>>(in, pitch);
    median_k<<<(NFRAMES + 255) / 256, 256, 0, stream>>>(pitch, out);
}